// Round 2
// baseline (494.283 us; speedup 1.0000x reference)
//
#include <hip/hip_runtime.h>
#include <hip/hip_bf16.h>
#include <stdint.h>

// Problem constants
#define BB 4
#define TT 2048
#define DD 1024
#define HH 16
#define HDD 64
// derived
#define M1 (BB*TT)      // 8192 rows
#define N1 (3*DD)       // 3072
#define KDIM DD         // 1024

typedef __attribute__((ext_vector_type(8))) short short8;   // 8 bf16 MFMA operand
typedef __attribute__((ext_vector_type(4))) float f32x4;

#if __has_builtin(__builtin_amdgcn_exp2f)
#define EXP2(x) __builtin_amdgcn_exp2f(x)
#else
#define EXP2(x) exp2f(x)
#endif

// async global->LDS, 16B per lane (global_load_lds_dwordx4)
#define GLOAD_LDS16(gp, lp) \
    __builtin_amdgcn_global_load_lds( \
        (const __attribute__((address_space(1))) void*)(gp), \
        (__attribute__((address_space(3))) void*)(lp), 16, 0, 0)

__device__ __forceinline__ float bf2f(unsigned short u) {
    union { uint32_t u32; float f; } c; c.u32 = ((uint32_t)u) << 16; return c.f;
}
__device__ __forceinline__ unsigned short f2bf(float f) {
    union { float f; uint32_t u32; } c; c.f = f;
    uint32_t u = c.u32;
    return (unsigned short)((u + 0x7FFFu + ((u >> 16) & 1u)) >> 16);  // RNE
}

// DPP row_ror rotate-reduce within the 16-lane DPP row (= one quad's l16 span).
// VALU-only — replaces __shfl_xor(...,16) which compiles to ds_swizzle (LDS pipe).
template <int CTRL>
__device__ __forceinline__ float dpp_ror(float x) {
    union { float f; int i; } u, r;
    u.f = x;
    r.i = __builtin_amdgcn_update_dpp(u.i, u.i, CTRL, 0xF, 0xF, false);
    return r.f;
}
__device__ __forceinline__ float red_max16(float x) {
    x = fmaxf(x, dpp_ror<0x128>(x));   // row_ror:8
    x = fmaxf(x, dpp_ror<0x124>(x));   // row_ror:4
    x = fmaxf(x, dpp_ror<0x122>(x));   // row_ror:2
    x = fmaxf(x, dpp_ror<0x121>(x));   // row_ror:1
    return x;
}
__device__ __forceinline__ float red_sum16(float x) {
    x += dpp_ror<0x128>(x);
    x += dpp_ror<0x124>(x);
    x += dpp_ror<0x122>(x);
    x += dpp_ror<0x121>(x);
    return x;
}

// ---------------- elementwise fp32 -> bf16 (x), 4 elems/thread ----------------
__global__ __launch_bounds__(256) void cvt_f32_bf16(
    const float* __restrict__ in, unsigned short* __restrict__ out, int n4)
{
    int i = blockIdx.x * 256 + threadIdx.x;
    if (i >= n4) return;
    float4 v = *(const float4*)&in[(size_t)i * 4];
    ushort4 o;
    o.x = f2bf(v.x); o.y = f2bf(v.y); o.z = f2bf(v.z); o.w = f2bf(v.w);
    *(ushort4*)&out[(size_t)i * 4] = o;
}

// ---------------- transpose+convert: in fp32 [R][C] -> out bf16 [C][R] ----------------
__global__ __launch_bounds__(256) void transpose_f32_bf16(
    const float* __restrict__ in, unsigned short* __restrict__ out,
    int R, int C)
{
    __shared__ unsigned short tile[32][33];
    int bx = blockIdx.x;
    int by = blockIdx.y;
    int x = bx*32 + threadIdx.x;
    int y0 = by*32 + threadIdx.y;
    #pragma unroll
    for (int i = 0; i < 32; i += 8)
        tile[threadIdx.y + i][threadIdx.x] = f2bf(in[(size_t)(y0 + i)*C + x]);
    __syncthreads();
    int xo = by*32 + threadIdx.x;
    int yo = bx*32 + threadIdx.y;
    #pragma unroll
    for (int i = 0; i < 32; i += 8)
        out[(size_t)(yo + i)*R + xo] = tile[threadIdx.x][threadIdx.y + i];
}

// ---------------- MFMA bf16 GEMM ----------------
// MODE 1: f32 C[M][N]
// MODE 2: QKV-split — n<2048 -> bf16 QK[M][2048]; n>=2048 -> V transposed via
//         LDS to VT[((b*16+h)*64+d)][2048]+t with fully-coalesced 16B stores.
// Staging via global_load_lds width=16 (m97 pattern).
#define TSTR 132
template <int MODE>
__global__ __launch_bounds__(256) void gemm_bf16_mfma(
    const unsigned short* __restrict__ A, const unsigned short* __restrict__ BT,
    const float* __restrict__ bias, void* __restrict__ Cout, void* __restrict__ Cout2,
    int M, int N, int K)
{
    constexpr int SHSZ = (MODE == 2) ? 128*TSTR : 128*64;
    __shared__ __align__(16) unsigned short Sh[SHSZ];
    unsigned short* As = Sh;            // 128*32 shorts
    unsigned short* Bs = Sh + 128*32;   // 128*32 shorts
    const int tid  = threadIdx.x;
    const int lane = tid & 63;
    const int wave = tid >> 6;
    const int wm = wave >> 1, wn = wave & 1;
    const int quad = lane >> 4, l16 = lane & 15;
    const int m0 = blockIdx.y * 128, n0 = blockIdx.x * 128;

    f32x4 acc[4][4] = {};

    const int nk = K >> 5;
    for (int kt = 0; kt < nk; ++kt) {
        const int k0 = kt << 5;
        __syncthreads();
        #pragma unroll
        for (int h = 0; h < 2; ++h) {
            int c = tid + h*256;
            int row = c >> 2, seg = c & 3;
            GLOAD_LDS16(&A[(size_t)(m0 + row)*K + k0 + seg*8], &As[row*32 + seg*8]);
            GLOAD_LDS16(&BT[(size_t)(n0 + row)*K + k0 + seg*8], &Bs[row*32 + seg*8]);
        }
        __syncthreads();   // compiler drains vmcnt before barrier
        short8 af[4], bf[4];
        #pragma unroll
        for (int mi = 0; mi < 4; ++mi)
            af[mi] = *(short8*)&As[(wm*64 + mi*16 + l16)*32 + quad*8];
        #pragma unroll
        for (int ni = 0; ni < 4; ++ni)
            bf[ni] = *(short8*)&Bs[(wn*64 + ni*16 + l16)*32 + quad*8];
        #pragma unroll
        for (int mi = 0; mi < 4; ++mi)
            #pragma unroll
            for (int ni = 0; ni < 4; ++ni)
                acc[mi][ni] = __builtin_amdgcn_mfma_f32_16x16x32_bf16(
                    af[mi], bf[ni], acc[mi][ni], 0, 0, 0);
    }

    if (MODE == 2 && n0 >= 2048) {
        // V third: transpose through LDS, then coalesced 16B stores to VT[d-row][t]
        __syncthreads();   // all As/Bs reads done before aliasing Sh
        #pragma unroll
        for (int ni = 0; ni < 4; ++ni) {
            int nl = wn*64 + ni*16 + l16;        // local n 0..127
            float bv = bias[n0 + nl];
            #pragma unroll
            for (int mi = 0; mi < 4; ++mi) {
                ushort4 pk;
                pk.x = f2bf(acc[mi][ni][0] + bv);
                pk.y = f2bf(acc[mi][ni][1] + bv);
                pk.z = f2bf(acc[mi][ni][2] + bv);
                pk.w = f2bf(acc[mi][ni][3] + bv);
                *(ushort4*)&Sh[nl*TSTR + wm*64 + mi*16 + quad*4] = pk;
            }
        }
        __syncthreads();
        const int bb = m0 >> 11, t0 = m0 & 2047;
        #pragma unroll
        for (int p = 0; p < 8; ++p) {
            int c = tid + p*256;
            int row = c >> 4, ch = c & 15;       // row: local n, ch: 8-short chunk of m
            int nv = n0 + row - 2048;            // 0..1023
            int hv = nv >> 6, dv = nv & 63;
            *(uint4*)&((unsigned short*)Cout2)[((size_t)((bb*16 + hv)*64 + dv))*2048 + t0 + ch*8] =
                *(uint4*)&Sh[row*TSTR + ch*8];
        }
        return;
    }

    const int cstride = (MODE == 2) ? 2048 : N;
    #pragma unroll
    for (int ni = 0; ni < 4; ++ni) {
        int n = n0 + wn*64 + ni*16 + l16;
        float bv = bias[n];
        #pragma unroll
        for (int mi = 0; mi < 4; ++mi) {
            #pragma unroll
            for (int r = 0; r < 4; ++r) {
                int m = m0 + wm*64 + mi*16 + quad*4 + r;
                float val = acc[mi][ni][r] + bv;
                if (MODE == 1)
                    ((float*)Cout)[(size_t)m*cstride + n] = val;
                else
                    ((unsigned short*)Cout)[(size_t)m*cstride + n] = f2bf(val);
            }
        }
    }
}

// ---------------- MFMA flash attention: 4-wave block, LDS-staged K ----------------
// Round-1 post-mortem: occupancy 16.7% (LDS 50KB -> 3 blocks/CU) and the qc
// mapping gave each CU 4 blocks of the SAME qc (i, i+256,... share (j>>3)&15
// phase) -> 16x work skew between CUs. Fixes this round:
//  - Balanced qc: alternating 256-block slabs flip the qc order, so a CU's
//    resident blocks pair {x, 15-x} -> uniform ~72 k-tiles/CU.
//  - V frags read straight from global (L2-pinned 512KB/bh per XCD; guide
//    common-mistake #7: don't LDS-stage L2-fit data). Issued at tile top,
//    latency hides under QK+softmax. LDS 50KB -> 34.8KB -> 4 blocks/CU,
//    __launch_bounds__(256,4) (VGPR 76 fits 128 budget).
//  - K stays LDS-staged (shared by 4 waves), double-buffered, 2-phase
//    pipeline with raw s_barrier + vmcnt(0) (one barrier per tile).
//  - Defer-max (T13, THR=8 in exp2 domain): wave-uniform __any skip of
//    alpha/rescale pass when the running max doesn't grow.
//  - s_setprio(1) around MFMA clusters (T5).
#define PST 72
__global__ __launch_bounds__(256, 4) void attn_mfma(
    const unsigned short* __restrict__ QK, const unsigned short* __restrict__ VT,
    unsigned short* __restrict__ Y)
{
    // LDS: K dbuf 2x4096 shorts (16KB), P 4 waves x 32 x PST (18KB)
    __shared__ __align__(16) unsigned short Sh[8192 + 4*32*PST];

    const int tid  = threadIdx.x;
    const int lane = tid & 63;
    const int wave = tid >> 6;
    const int quad = lane >> 4, l16 = lane & 15;

    const int i = blockIdx.x;
    const int xcd = i & 7, j = i >> 3;
    const int g = j & 15;
    const int qc = ((j >> 5) & 1) ? g : 15 - g;   // balanced: CU pairs {x,15-x}
    const int bh = xcd + 8*(j >> 4);
    const int b = bh >> 4, h = bh & 15;
    const int q0w = qc*128 + wave*32;
    const size_t qkbase = (size_t)(b*TT) * 2048;
    const size_t vbase  = (size_t)(bh*64) * 2048;
    const int qcol = h*64, kcol = 1024 + h*64;
    const float C2 = 0.18033688011112042f;   // (1/sqrt(64)) * log2(e)

    unsigned short* Pw = &Sh[8192 + wave*(32*PST)];

    // Q fragments straight from global (held for the whole loop)
    short8 aq[2][2];
    #pragma unroll
    for (int mt = 0; mt < 2; ++mt)
        #pragma unroll
        for (int kk = 0; kk < 2; ++kk)
            aq[mt][kk] = *(const short8*)&QK[qkbase + (size_t)(q0w + mt*16 + l16)*2048
                                            + qcol + kk*32 + quad*8];

    f32x4 o[2][4] = {};
    float mold[2][4], lsum[2][4];
    #pragma unroll
    for (int mt = 0; mt < 2; ++mt)
        #pragma unroll
        for (int r = 0; r < 4; ++r) { mold[mt][r] = -3.0e38f; lsum[mt][r] = 0.0f; }

    const int nkt = 2*qc + 2;                  // block-uniform k-tile count

    // stage K tile kt into buffer buf; dest linear in lane, source pre-swizzled
    auto STAGE = [&](int buf, int kt) {
        const int k0 = kt << 6;
        unsigned short* Kb = &Sh[buf*4096];
        #pragma unroll
        for (int p = 0; p < 2; ++p) {
            int c = p*256 + tid;               // 16B chunk index, linear in lane
            int r = c >> 3;
            int ch = (c & 7) ^ (r & 7);        // source chunk (inverse swizzle)
            GLOAD_LDS16(&QK[qkbase + (size_t)(k0 + r)*2048 + kcol + ch*8], &Kb[c*8]);
        }
    };

    STAGE(0, 0);
    asm volatile("s_waitcnt vmcnt(0)" ::: "memory");
    __builtin_amdgcn_s_barrier();

    int cur = 0;
    for (int kt = 0; kt < nkt; ++kt) {
        const int k0 = kt * 64;
        if (kt + 1 < nkt) STAGE(cur ^ 1, kt + 1);   // async prefetch next K tile

        if (k0 <= q0w + 31) {                  // wave-uniform causal activity guard
            const unsigned short* Kb = &Sh[cur*4096];

            // ---- V frags from global (L2), issued early: hide under QK+softmax
            short8 bv[2][4];
            #pragma unroll
            for (int kk = 0; kk < 2; ++kk)
                #pragma unroll
                for (int dt = 0; dt < 4; ++dt)
                    bv[kk][dt] = *(const short8*)&VT[vbase + (size_t)(dt*16 + l16)*2048
                                                     + k0 + kk*32 + quad*8];

            // ---- S = Q K^T from LDS (swizzled reads)
            f32x4 s[2][4];
            __builtin_amdgcn_s_setprio(1);
            #pragma unroll
            for (int nt = 0; nt < 4; ++nt) {
                if (k0 + nt*16 <= q0w + 31) {
                    f32x4 z = {};
                    s[0][nt] = z; s[1][nt] = z;
                    #pragma unroll
                    for (int kk = 0; kk < 2; ++kk) {
                        int r = nt*16 + l16;
                        short8 bk = *(const short8*)&Kb[r*64 + (((kk*4 + quad) ^ (r & 7))*8)];
                        s[0][nt] = __builtin_amdgcn_mfma_f32_16x16x32_bf16(aq[0][kk], bk, s[0][nt], 0, 0, 0);
                        s[1][nt] = __builtin_amdgcn_mfma_f32_16x16x32_bf16(aq[1][kk], bk, s[1][nt], 0, 0, 0);
                    }
                } else {
                    #pragma unroll
                    for (int r = 0; r < 4; ++r) { s[0][nt][r] = -3.0e38f; s[1][nt][r] = -3.0e38f; }
                }
            }
            __builtin_amdgcn_s_setprio(0);

            // ---- element causal mask (straddling tiles only)
            if (k0 + 63 > q0w) {
                #pragma unroll
                for (int mt = 0; mt < 2; ++mt)
                    #pragma unroll
                    for (int nt = 0; nt < 4; ++nt)
                        #pragma unroll
                        for (int r = 0; r < 4; ++r) {
                            int kg = k0 + nt*16 + l16;
                            int qg = q0w + mt*16 + quad*4 + r;
                            if (kg > qg) s[mt][nt][r] = -3.0e38f;
                        }
            }

            // ---- online softmax (exp2 domain), DPP reductions, defer-max (T13)
            float pm[2][4];
            #pragma unroll
            for (int mt = 0; mt < 2; ++mt)
                #pragma unroll
                for (int r = 0; r < 4; ++r) {
                    float rm = fmaxf(fmaxf(s[mt][0][r], s[mt][1][r]),
                                     fmaxf(s[mt][2][r], s[mt][3][r]));
                    pm[mt][r] = red_max16(rm) * C2;
                }
            int need = 0;
            #pragma unroll
            for (int mt = 0; mt < 2; ++mt)
                #pragma unroll
                for (int r = 0; r < 4; ++r)
                    need |= (pm[mt][r] > mold[mt][r] + 8.0f);
            if (__any(need)) {
                #pragma unroll
                for (int mt = 0; mt < 2; ++mt)
                    #pragma unroll
                    for (int r = 0; r < 4; ++r) {
                        float m2 = fmaxf(mold[mt][r], pm[mt][r]);
                        float al = EXP2(mold[mt][r] - m2);
                        mold[mt][r] = m2;
                        lsum[mt][r] *= al;
                        #pragma unroll
                        for (int dt = 0; dt < 4; ++dt)
                            o[mt][dt][r] *= al;
                    }
            }
            float rs[2][4] = {};
            #pragma unroll
            for (int mt = 0; mt < 2; ++mt)
                #pragma unroll
                for (int nt = 0; nt < 4; ++nt)
                    #pragma unroll
                    for (int r = 0; r < 4; ++r) {
                        float p = EXP2(fmaf(s[mt][nt][r], C2, -mold[mt][r]));
                        s[mt][nt][r] = p;
                        rs[mt][r] += p;
                    }
            #pragma unroll
            for (int mt = 0; mt < 2; ++mt)
                #pragma unroll
                for (int r = 0; r < 4; ++r)
                    lsum[mt][r] += red_sum16(rs[mt][r]);

            // ---- P -> LDS (wave-private buffer; same-wave RAW, no barrier)
            #pragma unroll
            for (int mt = 0; mt < 2; ++mt)
                #pragma unroll
                for (int nt = 0; nt < 4; ++nt)
                    #pragma unroll
                    for (int r = 0; r < 4; ++r) {
                        union { float f; uint32_t u; } c; c.f = s[mt][nt][r];
                        Pw[(mt*16 + quad*4 + r)*PST + nt*16 + l16] =
                            (unsigned short)((c.u + 0x8000u) >> 16);
                    }

            // ---- O += P V
            __builtin_amdgcn_s_setprio(1);
            #pragma unroll
            for (int kk = 0; kk < 2; ++kk) {
                short8 ap0 = *(short8*)&Pw[(     l16)*PST + kk*32 + quad*8];
                short8 ap1 = *(short8*)&Pw[(16 + l16)*PST + kk*32 + quad*8];
                #pragma unroll
                for (int dt = 0; dt < 4; ++dt) {
                    o[0][dt] = __builtin_amdgcn_mfma_f32_16x16x32_bf16(ap0, bv[kk][dt], o[0][dt], 0, 0, 0);
                    o[1][dt] = __builtin_amdgcn_mfma_f32_16x16x32_bf16(ap1, bv[kk][dt], o[1][dt], 0, 0, 0);
                }
            }
            __builtin_amdgcn_s_setprio(0);
        }

        asm volatile("s_waitcnt vmcnt(0)" ::: "memory");  // next-tile K stage landed
        __builtin_amdgcn_s_barrier();                     // all waves' stage + reads done
        cur ^= 1;
    }

    // ---- normalize + store (bf16 intermediate Y)
    #pragma unroll
    for (int mt = 0; mt < 2; ++mt)
        #pragma unroll
        for (int r = 0; r < 4; ++r) {
            float inv = 1.0f / lsum[mt][r];
            int t = q0w + mt*16 + quad*4 + r;
            #pragma unroll
            for (int dt = 0; dt < 4; ++dt)
                Y[((size_t)(b*TT + t))*DD + h*64 + dt*16 + l16] = f2bf(o[mt][dt][r] * inv);
        }
}

extern "C" void kernel_launch(void* const* d_in, const int* in_sizes, int n_in,
                              void* d_out, int out_size, void* d_ws, size_t ws_size,
                              hipStream_t stream)
{
    const float* x    = (const float*)d_in[0];   // [4,2048,1024] fp32
    // d_in[1] = causal_mask (int32) — causality implemented analytically, unused
    const float* wqkv = (const float*)d_in[2];   // [1024][3072] fp32
    const float* bqkv = (const float*)d_in[3];   // [3072] fp32
    const float* wout = (const float*)d_in[4];   // [1024][1024] fp32
    const float* bout = (const float*)d_in[5];   // [1024] fp32
    float* out = (float*)d_out;                  // [4,2048,1024] fp32

    char* ws = (char*)d_ws;
    unsigned short* Xb    = (unsigned short*)ws;                    // 16 MB
    unsigned short* WqkvT = (unsigned short*)(ws + 16777216);       // 6 MB
    unsigned short* WoutT = (unsigned short*)(ws + 23068672);       // 2 MB
    unsigned short* QK    = (unsigned short*)(ws + 25165824);       // 32 MB [M][2048]
    unsigned short* VTb   = (unsigned short*)(ws + 58720256);       // 16 MB [(bh*64+d)][2048]
    unsigned short* Ybuf  = (unsigned short*)(ws + 75497472);       // 16 MB

    cvt_f32_bf16<<<(M1*KDIM/4 + 255)/256, 256, 0, stream>>>(x, Xb, M1*KDIM/4);
    transpose_f32_bf16<<<dim3(N1/32, KDIM/32), dim3(32, 8), 0, stream>>>(wqkv, WqkvT, KDIM, N1);
    transpose_f32_bf16<<<dim3(DD/32, KDIM/32), dim3(32, 8), 0, stream>>>(wout, WoutT, KDIM, DD);
    gemm_bf16_mfma<2><<<dim3(N1/128, M1/128), 256, 0, stream>>>(Xb, WqkvT, bqkv, QK, VTb, M1, N1, KDIM);
    attn_mfma<<<dim3(1024), 256, 0, stream>>>(QK, VTb, Ybuf);
    gemm_bf16_mfma<1><<<dim3(DD/128, M1/128), 256, 0, stream>>>(Ybuf, WoutT, bout, out, nullptr, M1, DD, KDIM);
}

// Round 3
// 400.860 us; speedup vs baseline: 1.2331x; 1.2331x over previous
//
#include <hip/hip_runtime.h>
#include <hip/hip_bf16.h>
#include <stdint.h>

// Problem constants
#define BB 4
#define TT 2048
#define DD 1024
#define HH 16
#define HDD 64
// derived
#define M1 (BB*TT)      // 8192 rows
#define N1 (3*DD)       // 3072
#define KDIM DD         // 1024

typedef __attribute__((ext_vector_type(8))) short short8;   // 8 bf16 MFMA operand
typedef __attribute__((ext_vector_type(4))) float f32x4;

#if __has_builtin(__builtin_amdgcn_exp2f)
#define EXP2(x) __builtin_amdgcn_exp2f(x)
#else
#define EXP2(x) exp2f(x)
#endif

// async global->LDS, 16B per lane (global_load_lds_dwordx4)
#define GLOAD_LDS16(gp, lp) \
    __builtin_amdgcn_global_load_lds( \
        (const __attribute__((address_space(1))) void*)(gp), \
        (__attribute__((address_space(3))) void*)(lp), 16, 0, 0)

__device__ __forceinline__ float bf2f(unsigned short u) {
    union { uint32_t u32; float f; } c; c.u32 = ((uint32_t)u) << 16; return c.f;
}
__device__ __forceinline__ unsigned short f2bf(float f) {
    union { float f; uint32_t u32; } c; c.f = f;
    uint32_t u = c.u32;
    return (unsigned short)((u + 0x7FFFu + ((u >> 16) & 1u)) >> 16);  // RNE
}

// DPP row_ror rotate-reduce within the 16-lane DPP row (= one quad's l16 span).
// VALU-only — replaces __shfl_xor(...,16) which compiles to ds_swizzle (LDS pipe).
template <int CTRL>
__device__ __forceinline__ float dpp_ror(float x) {
    union { float f; int i; } u, r;
    u.f = x;
    r.i = __builtin_amdgcn_update_dpp(u.i, u.i, CTRL, 0xF, 0xF, false);
    return r.f;
}
__device__ __forceinline__ float red_max16(float x) {
    x = fmaxf(x, dpp_ror<0x128>(x));   // row_ror:8
    x = fmaxf(x, dpp_ror<0x124>(x));   // row_ror:4
    x = fmaxf(x, dpp_ror<0x122>(x));   // row_ror:2
    x = fmaxf(x, dpp_ror<0x121>(x));   // row_ror:1
    return x;
}
__device__ __forceinline__ float red_sum16(float x) {
    x += dpp_ror<0x128>(x);
    x += dpp_ror<0x124>(x);
    x += dpp_ror<0x122>(x);
    x += dpp_ror<0x121>(x);
    return x;
}

// ---------------- elementwise fp32 -> bf16 (x), 4 elems/thread ----------------
__global__ __launch_bounds__(256) void cvt_f32_bf16(
    const float* __restrict__ in, unsigned short* __restrict__ out, int n4)
{
    int i = blockIdx.x * 256 + threadIdx.x;
    if (i >= n4) return;
    float4 v = *(const float4*)&in[(size_t)i * 4];
    ushort4 o;
    o.x = f2bf(v.x); o.y = f2bf(v.y); o.z = f2bf(v.z); o.w = f2bf(v.w);
    *(ushort4*)&out[(size_t)i * 4] = o;
}

// ---------------- transpose+convert: in fp32 [R][C] -> out bf16 [C][R] ----------------
__global__ __launch_bounds__(256) void transpose_f32_bf16(
    const float* __restrict__ in, unsigned short* __restrict__ out,
    int R, int C)
{
    __shared__ unsigned short tile[32][33];
    int bx = blockIdx.x;
    int by = blockIdx.y;
    int x = bx*32 + threadIdx.x;
    int y0 = by*32 + threadIdx.y;
    #pragma unroll
    for (int i = 0; i < 32; i += 8)
        tile[threadIdx.y + i][threadIdx.x] = f2bf(in[(size_t)(y0 + i)*C + x]);
    __syncthreads();
    int xo = by*32 + threadIdx.x;
    int yo = bx*32 + threadIdx.y;
    #pragma unroll
    for (int i = 0; i < 32; i += 8)
        out[(size_t)(yo + i)*R + xo] = tile[threadIdx.x][threadIdx.y + i];
}

// ---------------- MFMA bf16 GEMM ----------------
// MODE 1: f32 C[M][N]
// MODE 2: QKV-split — n<2048 -> bf16 QK[M][2048]; n>=2048 -> V transposed via
//         LDS to VT[((b*16+h)*64+d)][2048]+t with fully-coalesced 16B stores.
// Staging via global_load_lds width=16 (m97 pattern).
#define TSTR 132
template <int MODE>
__global__ __launch_bounds__(256) void gemm_bf16_mfma(
    const unsigned short* __restrict__ A, const unsigned short* __restrict__ BT,
    const float* __restrict__ bias, void* __restrict__ Cout, void* __restrict__ Cout2,
    int M, int N, int K)
{
    constexpr int SHSZ = (MODE == 2) ? 128*TSTR : 128*64;
    __shared__ __align__(16) unsigned short Sh[SHSZ];
    unsigned short* As = Sh;            // 128*32 shorts
    unsigned short* Bs = Sh + 128*32;   // 128*32 shorts
    const int tid  = threadIdx.x;
    const int lane = tid & 63;
    const int wave = tid >> 6;
    const int wm = wave >> 1, wn = wave & 1;
    const int quad = lane >> 4, l16 = lane & 15;
    const int m0 = blockIdx.y * 128, n0 = blockIdx.x * 128;

    f32x4 acc[4][4] = {};

    const int nk = K >> 5;
    for (int kt = 0; kt < nk; ++kt) {
        const int k0 = kt << 5;
        __syncthreads();
        #pragma unroll
        for (int h = 0; h < 2; ++h) {
            int c = tid + h*256;
            int row = c >> 2, seg = c & 3;
            GLOAD_LDS16(&A[(size_t)(m0 + row)*K + k0 + seg*8], &As[row*32 + seg*8]);
            GLOAD_LDS16(&BT[(size_t)(n0 + row)*K + k0 + seg*8], &Bs[row*32 + seg*8]);
        }
        __syncthreads();   // compiler drains vmcnt before barrier
        short8 af[4], bf[4];
        #pragma unroll
        for (int mi = 0; mi < 4; ++mi)
            af[mi] = *(short8*)&As[(wm*64 + mi*16 + l16)*32 + quad*8];
        #pragma unroll
        for (int ni = 0; ni < 4; ++ni)
            bf[ni] = *(short8*)&Bs[(wn*64 + ni*16 + l16)*32 + quad*8];
        #pragma unroll
        for (int mi = 0; mi < 4; ++mi)
            #pragma unroll
            for (int ni = 0; ni < 4; ++ni)
                acc[mi][ni] = __builtin_amdgcn_mfma_f32_16x16x32_bf16(
                    af[mi], bf[ni], acc[mi][ni], 0, 0, 0);
    }

    if (MODE == 2 && n0 >= 2048) {
        // V third: transpose through LDS, then coalesced 16B stores to VT[d-row][t]
        __syncthreads();   // all As/Bs reads done before aliasing Sh
        #pragma unroll
        for (int ni = 0; ni < 4; ++ni) {
            int nl = wn*64 + ni*16 + l16;        // local n 0..127
            float bv = bias[n0 + nl];
            #pragma unroll
            for (int mi = 0; mi < 4; ++mi) {
                ushort4 pk;
                pk.x = f2bf(acc[mi][ni][0] + bv);
                pk.y = f2bf(acc[mi][ni][1] + bv);
                pk.z = f2bf(acc[mi][ni][2] + bv);
                pk.w = f2bf(acc[mi][ni][3] + bv);
                *(ushort4*)&Sh[nl*TSTR + wm*64 + mi*16 + quad*4] = pk;
            }
        }
        __syncthreads();
        const int bb = m0 >> 11, t0 = m0 & 2047;
        #pragma unroll
        for (int p = 0; p < 8; ++p) {
            int c = tid + p*256;
            int row = c >> 4, ch = c & 15;       // row: local n, ch: 8-short chunk of m
            int nv = n0 + row - 2048;            // 0..1023
            int hv = nv >> 6, dv = nv & 63;
            *(uint4*)&((unsigned short*)Cout2)[((size_t)((bb*16 + hv)*64 + dv))*2048 + t0 + ch*8] =
                *(uint4*)&Sh[row*TSTR + ch*8];
        }
        return;
    }

    const int cstride = (MODE == 2) ? 2048 : N;
    #pragma unroll
    for (int ni = 0; ni < 4; ++ni) {
        int n = n0 + wn*64 + ni*16 + l16;
        float bv = bias[n];
        #pragma unroll
        for (int mi = 0; mi < 4; ++mi) {
            #pragma unroll
            for (int r = 0; r < 4; ++r) {
                int m = m0 + wm*64 + mi*16 + quad*4 + r;
                float val = acc[mi][ni][r] + bv;
                if (MODE == 1)
                    ((float*)Cout)[(size_t)m*cstride + n] = val;
                else
                    ((unsigned short*)Cout)[(size_t)m*cstride + n] = f2bf(val);
            }
        }
    }
}

// ---------------- MFMA flash attention: 4-wave block, LDS-staged K ----------------
// Round-2 post-mortem: __launch_bounds__(256,4) = 128-reg unified budget.
// Live set ~150 regs -> compiler allocated 64 VGPR + spilled: FETCH 257MB,
// WRITE 371MB (scratch), attn 280us. THE register cliff dominates everything.
// This round: (256,3) = 170-reg budget, zero spill (round-1 structure fit).
// Occupancy 3 blocks/CU = 12 waves/CU, same as round 1, but keeping:
//  - Balanced qc: CU's resident blocks pair {x,15-x} -> uniform ~68 k-tiles/CU
//    (round 1 had 16x CU work skew: blocks i,i+256,.. shared the same qc).
//  - V frags from global/L2 (512KB/bh pinned per XCD; don't LDS-stage L2-fit
//    data). Issued right AFTER QK^T: live range spans only softmax (~400cy)
//    which still hides the ~300cy L2 latency, and keeps peak pressure low.
//  - K LDS-staged dbuf (shared by 4 waves), 2-phase pipeline, raw s_barrier +
//    vmcnt(0) once per tile.
//  - Defer-max (T13, THR=8) + s_setprio around MFMA clusters (T5).
#define PST 72
__global__ __launch_bounds__(256, 3) void attn_mfma(
    const unsigned short* __restrict__ QK, const unsigned short* __restrict__ VT,
    unsigned short* __restrict__ Y)
{
    // LDS: K dbuf 2x4096 shorts (16KB), P 4 waves x 32 x PST (18KB)
    __shared__ __align__(16) unsigned short Sh[8192 + 4*32*PST];

    const int tid  = threadIdx.x;
    const int lane = tid & 63;
    const int wave = tid >> 6;
    const int quad = lane >> 4, l16 = lane & 15;

    const int i = blockIdx.x;
    const int xcd = i & 7, j = i >> 3;
    const int g = j & 15;
    const int qc = ((j >> 5) & 1) ? g : 15 - g;   // balanced: CU pairs {x,15-x}
    const int bh = xcd + 8*(j >> 4);
    const int b = bh >> 4, h = bh & 15;
    const int q0w = qc*128 + wave*32;
    const size_t qkbase = (size_t)(b*TT) * 2048;
    const size_t vbase  = (size_t)(bh*64) * 2048;
    const int qcol = h*64, kcol = 1024 + h*64;
    const float C2 = 0.18033688011112042f;   // (1/sqrt(64)) * log2(e)

    unsigned short* Pw = &Sh[8192 + wave*(32*PST)];

    // Q fragments straight from global (held for the whole loop)
    short8 aq[2][2];
    #pragma unroll
    for (int mt = 0; mt < 2; ++mt)
        #pragma unroll
        for (int kk = 0; kk < 2; ++kk)
            aq[mt][kk] = *(const short8*)&QK[qkbase + (size_t)(q0w + mt*16 + l16)*2048
                                            + qcol + kk*32 + quad*8];

    f32x4 o[2][4] = {};
    float mold[2][4], lsum[2][4];
    #pragma unroll
    for (int mt = 0; mt < 2; ++mt)
        #pragma unroll
        for (int r = 0; r < 4; ++r) { mold[mt][r] = -3.0e38f; lsum[mt][r] = 0.0f; }

    const int nkt = 2*qc + 2;                  // block-uniform k-tile count

    // stage K tile kt into buffer buf; dest linear in lane, source pre-swizzled
    auto STAGE = [&](int buf, int kt) {
        const int k0 = kt << 6;
        unsigned short* Kb = &Sh[buf*4096];
        #pragma unroll
        for (int p = 0; p < 2; ++p) {
            int c = p*256 + tid;               // 16B chunk index, linear in lane
            int r = c >> 3;
            int ch = (c & 7) ^ (r & 7);        // source chunk (inverse swizzle)
            GLOAD_LDS16(&QK[qkbase + (size_t)(k0 + r)*2048 + kcol + ch*8], &Kb[c*8]);
        }
    };

    STAGE(0, 0);
    asm volatile("s_waitcnt vmcnt(0)" ::: "memory");
    __builtin_amdgcn_s_barrier();

    int cur = 0;
    for (int kt = 0; kt < nkt; ++kt) {
        const int k0 = kt * 64;
        if (kt + 1 < nkt) STAGE(cur ^ 1, kt + 1);   // async prefetch next K tile

        if (k0 <= q0w + 31) {                  // wave-uniform causal activity guard
            const unsigned short* Kb = &Sh[cur*4096];

            // ---- S = Q K^T from LDS (swizzled reads)
            f32x4 s[2][4];
            __builtin_amdgcn_s_setprio(1);
            #pragma unroll
            for (int nt = 0; nt < 4; ++nt) {
                if (k0 + nt*16 <= q0w + 31) {
                    f32x4 z = {};
                    s[0][nt] = z; s[1][nt] = z;
                    #pragma unroll
                    for (int kk = 0; kk < 2; ++kk) {
                        int r = nt*16 + l16;
                        short8 bk = *(const short8*)&Kb[r*64 + (((kk*4 + quad) ^ (r & 7))*8)];
                        s[0][nt] = __builtin_amdgcn_mfma_f32_16x16x32_bf16(aq[0][kk], bk, s[0][nt], 0, 0, 0);
                        s[1][nt] = __builtin_amdgcn_mfma_f32_16x16x32_bf16(aq[1][kk], bk, s[1][nt], 0, 0, 0);
                    }
                } else {
                    #pragma unroll
                    for (int r = 0; r < 4; ++r) { s[0][nt][r] = -3.0e38f; s[1][nt][r] = -3.0e38f; }
                }
            }
            __builtin_amdgcn_s_setprio(0);

            // ---- V frags from global (L2), issued now: latency hides under
            //      softmax; live range spans softmax only (register pressure)
            short8 bv[2][4];
            #pragma unroll
            for (int kk = 0; kk < 2; ++kk)
                #pragma unroll
                for (int dt = 0; dt < 4; ++dt)
                    bv[kk][dt] = *(const short8*)&VT[vbase + (size_t)(dt*16 + l16)*2048
                                                     + k0 + kk*32 + quad*8];

            // ---- element causal mask (straddling tiles only)
            if (k0 + 63 > q0w) {
                #pragma unroll
                for (int mt = 0; mt < 2; ++mt)
                    #pragma unroll
                    for (int nt = 0; nt < 4; ++nt)
                        #pragma unroll
                        for (int r = 0; r < 4; ++r) {
                            int kg = k0 + nt*16 + l16;
                            int qg = q0w + mt*16 + quad*4 + r;
                            if (kg > qg) s[mt][nt][r] = -3.0e38f;
                        }
            }

            // ---- online softmax (exp2 domain), DPP reductions, defer-max (T13)
            float pm[2][4];
            #pragma unroll
            for (int mt = 0; mt < 2; ++mt)
                #pragma unroll
                for (int r = 0; r < 4; ++r) {
                    float rm = fmaxf(fmaxf(s[mt][0][r], s[mt][1][r]),
                                     fmaxf(s[mt][2][r], s[mt][3][r]));
                    pm[mt][r] = red_max16(rm) * C2;
                }
            int need = 0;
            #pragma unroll
            for (int mt = 0; mt < 2; ++mt)
                #pragma unroll
                for (int r = 0; r < 4; ++r)
                    need |= (pm[mt][r] > mold[mt][r] + 8.0f);
            if (__any(need)) {
                #pragma unroll
                for (int mt = 0; mt < 2; ++mt)
                    #pragma unroll
                    for (int r = 0; r < 4; ++r) {
                        float m2 = fmaxf(mold[mt][r], pm[mt][r]);
                        float al = EXP2(mold[mt][r] - m2);
                        mold[mt][r] = m2;
                        lsum[mt][r] *= al;
                        #pragma unroll
                        for (int dt = 0; dt < 4; ++dt)
                            o[mt][dt][r] *= al;
                    }
            }
            float rs[2][4] = {};
            #pragma unroll
            for (int mt = 0; mt < 2; ++mt)
                #pragma unroll
                for (int nt = 0; nt < 4; ++nt)
                    #pragma unroll
                    for (int r = 0; r < 4; ++r) {
                        float p = EXP2(fmaf(s[mt][nt][r], C2, -mold[mt][r]));
                        s[mt][nt][r] = p;
                        rs[mt][r] += p;
                    }
            #pragma unroll
            for (int mt = 0; mt < 2; ++mt)
                #pragma unroll
                for (int r = 0; r < 4; ++r)
                    lsum[mt][r] += red_sum16(rs[mt][r]);

            // ---- P -> LDS (wave-private buffer; same-wave RAW, no barrier)
            #pragma unroll
            for (int mt = 0; mt < 2; ++mt)
                #pragma unroll
                for (int nt = 0; nt < 4; ++nt)
                    #pragma unroll
                    for (int r = 0; r < 4; ++r) {
                        union { float f; uint32_t u; } c; c.f = s[mt][nt][r];
                        Pw[(mt*16 + quad*4 + r)*PST + nt*16 + l16] =
                            (unsigned short)((c.u + 0x8000u) >> 16);
                    }

            // ---- O += P V
            __builtin_amdgcn_s_setprio(1);
            #pragma unroll
            for (int kk = 0; kk < 2; ++kk) {
                short8 ap0 = *(short8*)&Pw[(     l16)*PST + kk*32 + quad*8];
                short8 ap1 = *(short8*)&Pw[(16 + l16)*PST + kk*32 + quad*8];
                #pragma unroll
                for (int dt = 0; dt < 4; ++dt) {
                    o[0][dt] = __builtin_amdgcn_mfma_f32_16x16x32_bf16(ap0, bv[kk][dt], o[0][dt], 0, 0, 0);
                    o[1][dt] = __builtin_amdgcn_mfma_f32_16x16x32_bf16(ap1, bv[kk][dt], o[1][dt], 0, 0, 0);
                }
            }
            __builtin_amdgcn_s_setprio(0);
        }

        asm volatile("s_waitcnt vmcnt(0)" ::: "memory");  // next-tile K stage landed
        __builtin_amdgcn_s_barrier();                     // all waves' stage + reads done
        cur ^= 1;
    }

    // ---- normalize + store (bf16 intermediate Y)
    #pragma unroll
    for (int mt = 0; mt < 2; ++mt)
        #pragma unroll
        for (int r = 0; r < 4; ++r) {
            float inv = 1.0f / lsum[mt][r];
            int t = q0w + mt*16 + quad*4 + r;
            #pragma unroll
            for (int dt = 0; dt < 4; ++dt)
                Y[((size_t)(b*TT + t))*DD + h*64 + dt*16 + l16] = f2bf(o[mt][dt][r] * inv);
        }
}

extern "C" void kernel_launch(void* const* d_in, const int* in_sizes, int n_in,
                              void* d_out, int out_size, void* d_ws, size_t ws_size,
                              hipStream_t stream)
{
    const float* x    = (const float*)d_in[0];   // [4,2048,1024] fp32
    // d_in[1] = causal_mask (int32) — causality implemented analytically, unused
    const float* wqkv = (const float*)d_in[2];   // [1024][3072] fp32
    const float* bqkv = (const float*)d_in[3];   // [3072] fp32
    const float* wout = (const float*)d_in[4];   // [1024][1024] fp32
    const float* bout = (const float*)d_in[5];   // [1024] fp32
    float* out = (float*)d_out;                  // [4,2048,1024] fp32

    char* ws = (char*)d_ws;
    unsigned short* Xb    = (unsigned short*)ws;                    // 16 MB
    unsigned short* WqkvT = (unsigned short*)(ws + 16777216);       // 6 MB
    unsigned short* WoutT = (unsigned short*)(ws + 23068672);       // 2 MB
    unsigned short* QK    = (unsigned short*)(ws + 25165824);       // 32 MB [M][2048]
    unsigned short* VTb   = (unsigned short*)(ws + 58720256);       // 16 MB [(bh*64+d)][2048]
    unsigned short* Ybuf  = (unsigned short*)(ws + 75497472);       // 16 MB

    cvt_f32_bf16<<<(M1*KDIM/4 + 255)/256, 256, 0, stream>>>(x, Xb, M1*KDIM/4);
    transpose_f32_bf16<<<dim3(N1/32, KDIM/32), dim3(32, 8), 0, stream>>>(wqkv, WqkvT, KDIM, N1);
    transpose_f32_bf16<<<dim3(DD/32, KDIM/32), dim3(32, 8), 0, stream>>>(wout, WoutT, KDIM, DD);
    gemm_bf16_mfma<2><<<dim3(N1/128, M1/128), 256, 0, stream>>>(Xb, WqkvT, bqkv, QK, VTb, M1, N1, KDIM);
    attn_mfma<<<dim3(1024), 256, 0, stream>>>(QK, VTb, Ybuf);
    gemm_bf16_mfma<1><<<dim3(DD/128, M1/128), 256, 0, stream>>>(Ybuf, WoutT, bout, out, nullptr, M1, DD, KDIM);
}

// Round 4
// 335.237 us; speedup vs baseline: 1.4744x; 1.1958x over previous
//
#include <hip/hip_runtime.h>
#include <hip/hip_bf16.h>
#include <stdint.h>

// Problem constants
#define BB 4
#define TT 2048
#define DD 1024
#define HH 16
#define HDD 64
// derived
#define M1 (BB*TT)      // 8192 rows
#define N1 (3*DD)       // 3072
#define KDIM DD         // 1024

typedef __attribute__((ext_vector_type(8))) short short8;   // 8 bf16 MFMA operand
typedef __attribute__((ext_vector_type(4))) float f32x4;

#if __has_builtin(__builtin_amdgcn_exp2f)
#define EXP2(x) __builtin_amdgcn_exp2f(x)
#else
#define EXP2(x) exp2f(x)
#endif

// async global->LDS, 16B per lane (global_load_lds_dwordx4)
#define GLOAD_LDS16(gp, lp) \
    __builtin_amdgcn_global_load_lds( \
        (const __attribute__((address_space(1))) void*)(gp), \
        (__attribute__((address_space(3))) void*)(lp), 16, 0, 0)

__device__ __forceinline__ float bf2f(unsigned short u) {
    union { uint32_t u32; float f; } c; c.u32 = ((uint32_t)u) << 16; return c.f;
}
__device__ __forceinline__ unsigned short f2bf(float f) {
    union { float f; uint32_t u32; } c; c.f = f;
    uint32_t u = c.u32;
    return (unsigned short)((u + 0x7FFFu + ((u >> 16) & 1u)) >> 16);  // RNE
}

// DPP row_ror rotate-reduce within the 16-lane DPP row (= one quad's l16 span).
// VALU-only — replaces __shfl_xor(...,16) which compiles to ds_swizzle (LDS pipe).
template <int CTRL>
__device__ __forceinline__ float dpp_ror(float x) {
    union { float f; int i; } u, r;
    u.f = x;
    r.i = __builtin_amdgcn_update_dpp(u.i, u.i, CTRL, 0xF, 0xF, false);
    return r.f;
}
__device__ __forceinline__ float red_max16(float x) {
    x = fmaxf(x, dpp_ror<0x128>(x));   // row_ror:8
    x = fmaxf(x, dpp_ror<0x124>(x));   // row_ror:4
    x = fmaxf(x, dpp_ror<0x122>(x));   // row_ror:2
    x = fmaxf(x, dpp_ror<0x121>(x));   // row_ror:1
    return x;
}
__device__ __forceinline__ float red_sum16(float x) {
    x += dpp_ror<0x128>(x);
    x += dpp_ror<0x124>(x);
    x += dpp_ror<0x122>(x);
    x += dpp_ror<0x121>(x);
    return x;
}

// ---------------- elementwise fp32 -> bf16 (x), 4 elems/thread ----------------
__global__ __launch_bounds__(256) void cvt_f32_bf16(
    const float* __restrict__ in, unsigned short* __restrict__ out, int n4)
{
    int i = blockIdx.x * 256 + threadIdx.x;
    if (i >= n4) return;
    float4 v = *(const float4*)&in[(size_t)i * 4];
    ushort4 o;
    o.x = f2bf(v.x); o.y = f2bf(v.y); o.z = f2bf(v.z); o.w = f2bf(v.w);
    *(ushort4*)&out[(size_t)i * 4] = o;
}

// ---------------- transpose+convert: in fp32 [R][C] -> out bf16 [C][R] ----------------
__global__ __launch_bounds__(256) void transpose_f32_bf16(
    const float* __restrict__ in, unsigned short* __restrict__ out,
    int R, int C)
{
    __shared__ unsigned short tile[32][33];
    int bx = blockIdx.x;
    int by = blockIdx.y;
    int x = bx*32 + threadIdx.x;
    int y0 = by*32 + threadIdx.y;
    #pragma unroll
    for (int i = 0; i < 32; i += 8)
        tile[threadIdx.y + i][threadIdx.x] = f2bf(in[(size_t)(y0 + i)*C + x]);
    __syncthreads();
    int xo = by*32 + threadIdx.x;
    int yo = bx*32 + threadIdx.y;
    #pragma unroll
    for (int i = 0; i < 32; i += 8)
        out[(size_t)(yo + i)*R + xo] = tile[threadIdx.x][threadIdx.y + i];
}

// ---------------- MFMA bf16 GEMM ----------------
// MODE 1: f32 C[M][N]
// MODE 2: QKV-split — n<2048 -> bf16 QK[M][2048]; n>=2048 -> V transposed via
//         LDS to VT[((b*16+h)*64+d)][2048]+t with fully-coalesced 16B stores.
// Staging via global_load_lds width=16 (m97 pattern).
#define TSTR 132
template <int MODE>
__global__ __launch_bounds__(256) void gemm_bf16_mfma(
    const unsigned short* __restrict__ A, const unsigned short* __restrict__ BT,
    const float* __restrict__ bias, void* __restrict__ Cout, void* __restrict__ Cout2,
    int M, int N, int K)
{
    constexpr int SHSZ = (MODE == 2) ? 128*TSTR : 128*64;
    __shared__ __align__(16) unsigned short Sh[SHSZ];
    unsigned short* As = Sh;            // 128*32 shorts
    unsigned short* Bs = Sh + 128*32;   // 128*32 shorts
    const int tid  = threadIdx.x;
    const int lane = tid & 63;
    const int wave = tid >> 6;
    const int wm = wave >> 1, wn = wave & 1;
    const int quad = lane >> 4, l16 = lane & 15;
    const int m0 = blockIdx.y * 128, n0 = blockIdx.x * 128;

    f32x4 acc[4][4] = {};

    const int nk = K >> 5;
    for (int kt = 0; kt < nk; ++kt) {
        const int k0 = kt << 5;
        __syncthreads();
        #pragma unroll
        for (int h = 0; h < 2; ++h) {
            int c = tid + h*256;
            int row = c >> 2, seg = c & 3;
            GLOAD_LDS16(&A[(size_t)(m0 + row)*K + k0 + seg*8], &As[row*32 + seg*8]);
            GLOAD_LDS16(&BT[(size_t)(n0 + row)*K + k0 + seg*8], &Bs[row*32 + seg*8]);
        }
        __syncthreads();   // compiler drains vmcnt before barrier
        short8 af[4], bf[4];
        #pragma unroll
        for (int mi = 0; mi < 4; ++mi)
            af[mi] = *(short8*)&As[(wm*64 + mi*16 + l16)*32 + quad*8];
        #pragma unroll
        for (int ni = 0; ni < 4; ++ni)
            bf[ni] = *(short8*)&Bs[(wn*64 + ni*16 + l16)*32 + quad*8];
        #pragma unroll
        for (int mi = 0; mi < 4; ++mi)
            #pragma unroll
            for (int ni = 0; ni < 4; ++ni)
                acc[mi][ni] = __builtin_amdgcn_mfma_f32_16x16x32_bf16(
                    af[mi], bf[ni], acc[mi][ni], 0, 0, 0);
    }

    if (MODE == 2 && n0 >= 2048) {
        // V third: transpose through LDS, then coalesced 16B stores to VT[d-row][t]
        __syncthreads();   // all As/Bs reads done before aliasing Sh
        #pragma unroll
        for (int ni = 0; ni < 4; ++ni) {
            int nl = wn*64 + ni*16 + l16;        // local n 0..127
            float bv = bias[n0 + nl];
            #pragma unroll
            for (int mi = 0; mi < 4; ++mi) {
                ushort4 pk;
                pk.x = f2bf(acc[mi][ni][0] + bv);
                pk.y = f2bf(acc[mi][ni][1] + bv);
                pk.z = f2bf(acc[mi][ni][2] + bv);
                pk.w = f2bf(acc[mi][ni][3] + bv);
                *(ushort4*)&Sh[nl*TSTR + wm*64 + mi*16 + quad*4] = pk;
            }
        }
        __syncthreads();
        const int bb = m0 >> 11, t0 = m0 & 2047;
        #pragma unroll
        for (int p = 0; p < 8; ++p) {
            int c = tid + p*256;
            int row = c >> 4, ch = c & 15;       // row: local n, ch: 8-short chunk of m
            int nv = n0 + row - 2048;            // 0..1023
            int hv = nv >> 6, dv = nv & 63;
            *(uint4*)&((unsigned short*)Cout2)[((size_t)((bb*16 + hv)*64 + dv))*2048 + t0 + ch*8] =
                *(uint4*)&Sh[row*TSTR + ch*8];
        }
        return;
    }

    const int cstride = (MODE == 2) ? 2048 : N;
    #pragma unroll
    for (int ni = 0; ni < 4; ++ni) {
        int n = n0 + wn*64 + ni*16 + l16;
        float bv = bias[n];
        #pragma unroll
        for (int mi = 0; mi < 4; ++mi) {
            #pragma unroll
            for (int r = 0; r < 4; ++r) {
                int m = m0 + wm*64 + mi*16 + quad*4 + r;
                float val = acc[mi][ni][r] + bv;
                if (MODE == 1)
                    ((float*)Cout)[(size_t)m*cstride + n] = val;
                else
                    ((unsigned short*)Cout)[(size_t)m*cstride + n] = f2bf(val);
            }
        }
    }
}

// ---------------- MFMA flash attention: 4-wave block, LDS K+V, paired q-chunks ----
// Round-3 post-mortem: V-from-global regressed (PV's wait on V frags is
// younger than the K-stage gload_lds in the vmcnt queue -> draining V drains
// the prefetch every tile) and defer-max's branch re-introduced ~18MB scratch.
// Revert to the round-1 per-tile structure (141us measured: K AND V LDS-staged
// dbuf, DPP softmax, no defer-max, no mid-loop global loads). ONE change:
//  - Work balance by construction: each block processes the complementary
//    q-chunk PAIR (a, 15-a) of one (b,h) sequentially -> exactly
//    (2a+2)+(2(15-a)+2) = 34 k-tiles PER BLOCK, grid 512 = 2 blocks/CU.
//    Makespan is now independent of the (undefined) block->CU mapping
//    (round 1: co-resident blocks shared qc -> worst CU ran 128 tiles vs
//    68 avg). K/V staging pipeline runs across the pass boundary unchanged
//    (K/V tiles don't depend on the q-chunk); at the boundary: store pass-0
//    output, reload Q frags, reset softmax state.
// XCD pinning kept: i&7 -> all blocks of one bh-set on one XCD's L2.
#define PST 72
__global__ __launch_bounds__(256, 3) void attn_mfma(
    const unsigned short* __restrict__ QK, const unsigned short* __restrict__ VT,
    unsigned short* __restrict__ Y)
{
    // LDS: K dbuf 2x4096 shorts, V dbuf 2x4096 shorts, P 4 waves x 32 x PST
    __shared__ __align__(16) unsigned short Sh[16384 + 4*32*PST];

    const int tid  = threadIdx.x;
    const int lane = tid & 63;
    const int wave = tid >> 6;
    const int quad = lane >> 4, l16 = lane & 15;

    const int i = blockIdx.x;            // 0..511
    const int xcd = i & 7, j = i >> 3;   // j 0..63
    const int a = j & 7;                 // chunk-pair index: handles qc=a then 15-a
    const int bh = xcd + 8*(j >> 3 >> 0 & 0 ? 0 : (j >> 3));  // placeholder avoided below
    (void)bh;
    const int u = j >> 3;                // bh-group 0..7
    const int bh2 = xcd + 8*u;
    const int b = bh2 >> 4, h = bh2 & 15;
    const size_t qkbase = (size_t)(b*TT) * 2048;
    const size_t vbase  = (size_t)(bh2*64) * 2048;
    const int qcol = h*64, kcol = 1024 + h*64;
    const float C2 = 0.18033688011112042f;   // (1/sqrt(64)) * log2(e)

    unsigned short* Pw = &Sh[16384 + wave*(32*PST)];

    const int nk1 = 2*a + 2;             // pass-0 tile count (qc = a)
    const int ntot = 34;                 // nk1 + 2*(15-a)+2, uniform for all blocks

    short8 aq[2][2];
    f32x4 o[2][4];
    float mold[2][4], lsum[2][4];
    int q0w = a*128 + wave*32;           // current pass q-row base for this wave

    auto LOADQ = [&]() {
        #pragma unroll
        for (int mt = 0; mt < 2; ++mt)
            #pragma unroll
            for (int kk = 0; kk < 2; ++kk)
                aq[mt][kk] = *(const short8*)&QK[qkbase + (size_t)(q0w + mt*16 + l16)*2048
                                                + qcol + kk*32 + quad*8];
        #pragma unroll
        for (int mt = 0; mt < 2; ++mt)
            #pragma unroll
            for (int r = 0; r < 4; ++r) { mold[mt][r] = -3.0e38f; lsum[mt][r] = 0.0f; }
        #pragma unroll
        for (int mt = 0; mt < 2; ++mt)
            #pragma unroll
            for (int dt = 0; dt < 4; ++dt) { f32x4 z = {}; o[mt][dt] = z; }
    };
    auto FINALIZE = [&]() {
        #pragma unroll
        for (int mt = 0; mt < 2; ++mt)
            #pragma unroll
            for (int r = 0; r < 4; ++r) {
                float inv = 1.0f / lsum[mt][r];
                int tq = q0w + mt*16 + quad*4 + r;
                #pragma unroll
                for (int dt = 0; dt < 4; ++dt)
                    Y[((size_t)(b*TT + tq))*DD + h*64 + dt*16 + l16] = f2bf(o[mt][dt][r] * inv);
            }
    };

    // stage K/V tile (column window k0) into buffer buf; dest linear in lane,
    // source pre-swizzled (both-sides-or-neither rule)
    auto STAGE = [&](int buf, int k0) {
        unsigned short* Kb = &Sh[buf*4096];
        unsigned short* Vb = &Sh[8192 + buf*4096];
        #pragma unroll
        for (int p = 0; p < 2; ++p) {
            int c = p*256 + tid;               // 16B chunk index, linear in lane
            int r = c >> 3;
            int ch = (c & 7) ^ (r & 7);        // source chunk (inverse swizzle)
            GLOAD_LDS16(&QK[qkbase + (size_t)(k0 + r)*2048 + kcol + ch*8], &Kb[c*8]);
        }
        #pragma unroll
        for (int p = 0; p < 2; ++p) {
            int c = p*256 + tid;
            int r = c >> 3;                    // r = head-dim row of VT
            int ch = (c & 7) ^ (r & 7);
            GLOAD_LDS16(&VT[vbase + (size_t)r*2048 + k0 + ch*8], &Vb[c*8]);
        }
    };

    LOADQ();
    STAGE(0, 0);
    asm volatile("s_waitcnt vmcnt(0)" ::: "memory");
    __builtin_amdgcn_s_barrier();

    int cur = 0;
    for (int t = 0; t < ntot; ++t) {
        const int k0 = ((t < nk1) ? t : t - nk1) * 64;
        if (t + 1 < ntot) {
            const int t1 = t + 1;
            STAGE(cur ^ 1, ((t1 < nk1) ? t1 : t1 - nk1) * 64);   // async prefetch
        }
        if (t == nk1) {
            // pass boundary: finish chunk a, start chunk 15-a (block-uniform)
            FINALIZE();
            q0w = (15 - a)*128 + wave*32;
            LOADQ();
        }

        if (k0 <= q0w + 31) {                  // wave-uniform causal activity guard
            const unsigned short* Kb = &Sh[cur*4096];
            const unsigned short* Vb = &Sh[8192 + cur*4096];

            // ---- S = Q K^T from LDS (swizzled reads)
            f32x4 s[2][4];
            #pragma unroll
            for (int nt = 0; nt < 4; ++nt) {
                if (k0 + nt*16 <= q0w + 31) {
                    f32x4 z = {};
                    s[0][nt] = z; s[1][nt] = z;
                    #pragma unroll
                    for (int kk = 0; kk < 2; ++kk) {
                        int r = nt*16 + l16;
                        short8 bk = *(const short8*)&Kb[r*64 + (((kk*4 + quad) ^ (r & 7))*8)];
                        s[0][nt] = __builtin_amdgcn_mfma_f32_16x16x32_bf16(aq[0][kk], bk, s[0][nt], 0, 0, 0);
                        s[1][nt] = __builtin_amdgcn_mfma_f32_16x16x32_bf16(aq[1][kk], bk, s[1][nt], 0, 0, 0);
                    }
                } else {
                    #pragma unroll
                    for (int r = 0; r < 4; ++r) { s[0][nt][r] = -3.0e38f; s[1][nt][r] = -3.0e38f; }
                }
            }

            // ---- issue V-frag LDS loads now; latency hides under softmax
            short8 bv[2][4];
            #pragma unroll
            for (int kk = 0; kk < 2; ++kk)
                #pragma unroll
                for (int dt = 0; dt < 4; ++dt) {
                    int r = dt*16 + l16;
                    bv[kk][dt] = *(const short8*)&Vb[r*64 + (((kk*4 + quad) ^ (r & 7))*8)];
                }

            // ---- element causal mask (straddling tiles only)
            if (k0 + 63 > q0w) {
                #pragma unroll
                for (int mt = 0; mt < 2; ++mt)
                    #pragma unroll
                    for (int nt = 0; nt < 4; ++nt)
                        #pragma unroll
                        for (int r = 0; r < 4; ++r) {
                            int kg = k0 + nt*16 + l16;
                            int qg = q0w + mt*16 + quad*4 + r;
                            if (kg > qg) s[mt][nt][r] = -3.0e38f;
                        }
            }

            // ---- online softmax (exp2 domain), DPP reductions
            float m2n[2][4], al[2][4];
            #pragma unroll
            for (int mt = 0; mt < 2; ++mt)
                #pragma unroll
                for (int r = 0; r < 4; ++r) {
                    float rm = fmaxf(fmaxf(s[mt][0][r], s[mt][1][r]),
                                     fmaxf(s[mt][2][r], s[mt][3][r]));
                    rm = red_max16(rm);
                    float m2 = fmaxf(mold[mt][r], rm * C2);
                    al[mt][r]  = EXP2(mold[mt][r] - m2);
                    m2n[mt][r] = m2;
                }
            float rs[2][4] = {};
            #pragma unroll
            for (int mt = 0; mt < 2; ++mt)
                #pragma unroll
                for (int nt = 0; nt < 4; ++nt)
                    #pragma unroll
                    for (int r = 0; r < 4; ++r) {
                        float p = EXP2(fmaf(s[mt][nt][r], C2, -m2n[mt][r]));
                        s[mt][nt][r] = p;
                        rs[mt][r] += p;
                    }
            #pragma unroll
            for (int mt = 0; mt < 2; ++mt)
                #pragma unroll
                for (int r = 0; r < 4; ++r) {
                    float tsum = red_sum16(rs[mt][r]);
                    lsum[mt][r] = lsum[mt][r]*al[mt][r] + tsum;
                    mold[mt][r] = m2n[mt][r];
                }

            // ---- P -> LDS (wave-private buffer; same-wave RAW, no barrier)
            #pragma unroll
            for (int mt = 0; mt < 2; ++mt)
                #pragma unroll
                for (int nt = 0; nt < 4; ++nt)
                    #pragma unroll
                    for (int r = 0; r < 4; ++r) {
                        union { float f; uint32_t u; } c; c.f = s[mt][nt][r];
                        Pw[(mt*16 + quad*4 + r)*PST + nt*16 + l16] =
                            (unsigned short)((c.u + 0x8000u) >> 16);
                    }

            // ---- O = O*alpha + P V
            #pragma unroll
            for (int mt = 0; mt < 2; ++mt)
                #pragma unroll
                for (int dt = 0; dt < 4; ++dt)
                    #pragma unroll
                    for (int r = 0; r < 4; ++r)
                        o[mt][dt][r] *= al[mt][r];
            #pragma unroll
            for (int kk = 0; kk < 2; ++kk) {
                short8 ap0 = *(short8*)&Pw[(     l16)*PST + kk*32 + quad*8];
                short8 ap1 = *(short8*)&Pw[(16 + l16)*PST + kk*32 + quad*8];
                #pragma unroll
                for (int dt = 0; dt < 4; ++dt) {
                    o[0][dt] = __builtin_amdgcn_mfma_f32_16x16x32_bf16(ap0, bv[kk][dt], o[0][dt], 0, 0, 0);
                    o[1][dt] = __builtin_amdgcn_mfma_f32_16x16x32_bf16(ap1, bv[kk][dt], o[1][dt], 0, 0, 0);
                }
            }
        }

        asm volatile("s_waitcnt vmcnt(0)" ::: "memory");  // next-tile stage landed
        __builtin_amdgcn_s_barrier();                     // all waves' stage + reads done
        cur ^= 1;
    }

    FINALIZE();   // pass-1 (chunk 15-a) output
}

extern "C" void kernel_launch(void* const* d_in, const int* in_sizes, int n_in,
                              void* d_out, int out_size, void* d_ws, size_t ws_size,
                              hipStream_t stream)
{
    const float* x    = (const float*)d_in[0];   // [4,2048,1024] fp32
    // d_in[1] = causal_mask (int32) — causality implemented analytically, unused
    const float* wqkv = (const float*)d_in[2];   // [1024][3072] fp32
    const float* bqkv = (const float*)d_in[3];   // [3072] fp32
    const float* wout = (const float*)d_in[4];   // [1024][1024] fp32
    const float* bout = (const float*)d_in[5];   // [1024] fp32
    float* out = (float*)d_out;                  // [4,2048,1024] fp32

    char* ws = (char*)d_ws;
    unsigned short* Xb    = (unsigned short*)ws;                    // 16 MB
    unsigned short* WqkvT = (unsigned short*)(ws + 16777216);       // 6 MB
    unsigned short* WoutT = (unsigned short*)(ws + 23068672);       // 2 MB
    unsigned short* QK    = (unsigned short*)(ws + 25165824);       // 32 MB [M][2048]
    unsigned short* VTb   = (unsigned short*)(ws + 58720256);       // 16 MB [(bh*64+d)][2048]
    unsigned short* Ybuf  = (unsigned short*)(ws + 75497472);       // 16 MB

    cvt_f32_bf16<<<(M1*KDIM/4 + 255)/256, 256, 0, stream>>>(x, Xb, M1*KDIM/4);
    transpose_f32_bf16<<<dim3(N1/32, KDIM/32), dim3(32, 8), 0, stream>>>(wqkv, WqkvT, KDIM, N1);
    transpose_f32_bf16<<<dim3(DD/32, KDIM/32), dim3(32, 8), 0, stream>>>(wout, WoutT, KDIM, DD);
    gemm_bf16_mfma<2><<<dim3(N1/128, M1/128), 256, 0, stream>>>(Xb, WqkvT, bqkv, QK, VTb, M1, N1, KDIM);
    attn_mfma<<<dim3(512), 256, 0, stream>>>(QK, VTb, Ybuf);
    gemm_bf16_mfma<1><<<dim3(DD/128, M1/128), 256, 0, stream>>>(Ybuf, WoutT, bout, out, nullptr, M1, DD, KDIM);
}

// Round 5
// 333.602 us; speedup vs baseline: 1.4817x; 1.0049x over previous
//
#include <hip/hip_runtime.h>
#include <hip/hip_bf16.h>
#include <stdint.h>

// Problem constants
#define BB 4
#define TT 2048
#define DD 1024
#define HH 16
#define HDD 64
// derived
#define M1 (BB*TT)      // 8192 rows
#define N1 (3*DD)       // 3072
#define KDIM DD         // 1024

typedef __attribute__((ext_vector_type(8))) short short8;   // 8 bf16 MFMA operand
typedef __attribute__((ext_vector_type(4))) float f32x4;

#if __has_builtin(__builtin_amdgcn_exp2f)
#define EXP2(x) __builtin_amdgcn_exp2f(x)
#else
#define EXP2(x) exp2f(x)
#endif

// async global->LDS, 16B per lane (global_load_lds_dwordx4)
#define GLOAD_LDS16(gp, lp) \
    __builtin_amdgcn_global_load_lds( \
        (const __attribute__((address_space(1))) void*)(gp), \
        (__attribute__((address_space(3))) void*)(lp), 16, 0, 0)

__device__ __forceinline__ float bf2f(unsigned short u) {
    union { uint32_t u32; float f; } c; c.u32 = ((uint32_t)u) << 16; return c.f;
}
__device__ __forceinline__ unsigned short f2bf(float f) {
    union { float f; uint32_t u32; } c; c.f = f;
    uint32_t u = c.u32;
    return (unsigned short)((u + 0x7FFFu + ((u >> 16) & 1u)) >> 16);  // RNE
}

// DPP row_ror rotate-reduce within the 16-lane DPP row.
template <int CTRL>
__device__ __forceinline__ float dpp_ror(float x) {
    union { float f; int i; } u, r;
    u.f = x;
    r.i = __builtin_amdgcn_update_dpp(u.i, u.i, CTRL, 0xF, 0xF, false);
    return r.f;
}
__device__ __forceinline__ float red_max16(float x) {
    x = fmaxf(x, dpp_ror<0x128>(x));   // row_ror:8
    x = fmaxf(x, dpp_ror<0x124>(x));   // row_ror:4
    x = fmaxf(x, dpp_ror<0x122>(x));   // row_ror:2
    x = fmaxf(x, dpp_ror<0x121>(x));   // row_ror:1
    return x;
}
__device__ __forceinline__ float red_sum16(float x) {
    x += dpp_ror<0x128>(x);
    x += dpp_ror<0x124>(x);
    x += dpp_ror<0x122>(x);
    x += dpp_ror<0x121>(x);
    return x;
}

// ---------------- elementwise fp32 -> bf16 (x), 4 elems/thread ----------------
__global__ __launch_bounds__(256) void cvt_f32_bf16(
    const float* __restrict__ in, unsigned short* __restrict__ out, int n4)
{
    int i = blockIdx.x * 256 + threadIdx.x;
    if (i >= n4) return;
    float4 v = *(const float4*)&in[(size_t)i * 4];
    ushort4 o;
    o.x = f2bf(v.x); o.y = f2bf(v.y); o.z = f2bf(v.z); o.w = f2bf(v.w);
    *(ushort4*)&out[(size_t)i * 4] = o;
}

// ---------------- transpose+convert: in fp32 [R][C] -> out bf16 [C][R] ----------------
__global__ __launch_bounds__(256) void transpose_f32_bf16(
    const float* __restrict__ in, unsigned short* __restrict__ out,
    int R, int C)
{
    __shared__ unsigned short tile[32][33];
    int bx = blockIdx.x;
    int by = blockIdx.y;
    int x = bx*32 + threadIdx.x;
    int y0 = by*32 + threadIdx.y;
    #pragma unroll
    for (int i = 0; i < 32; i += 8)
        tile[threadIdx.y + i][threadIdx.x] = f2bf(in[(size_t)(y0 + i)*C + x]);
    __syncthreads();
    int xo = by*32 + threadIdx.x;
    int yo = bx*32 + threadIdx.y;
    #pragma unroll
    for (int i = 0; i < 32; i += 8)
        out[(size_t)(yo + i)*R + xo] = tile[threadIdx.x][threadIdx.y + i];
}

// ---------------- 256x256 MFMA bf16 GEMM, counted-vmcnt pipeline ----------------
// Round-4 post-mortem: attn is 122us; the two 128^2-tile GEMMs (m97 structure,
// 2 drain-barriers per 32-K step) are ~190us of the remaining 213 -> biggest
// lever. This kernel: BM=BN=256, BK=64, 8 waves (2m x 4n), 512 thr, 1 block/CU.
//  - A/B LDS double-buffer per K-tile (128 KB), staged via global_load_lds x16B.
//  - T2 swizzle: chunk ^= row&7 on stage SOURCE + same XOR on ds_read_b128
//    (both-sides rule; proven in attn kernel: 16-way conflict -> free).
//  - T4 counted vmcnt: STAGE(t+2) issued after the tile's last read phase;
//    tile-top s_waitcnt vmcnt(8) (next tile's 8 loads stay in flight) + raw
//    s_barrier + sched_barrier(0). Never vmcnt(0) in the loop.
//  - 4 quadrant phases per tile, each {ds_read, barrier, setprio(1), 16 MFMA,
//    setprio(0), barrier}; A frags reused 2 phases, B n-lo reloaded in ph3.
//  - Race-freedom: ds_read(tile t) after vmcnt(8)+barrier guarantees stage(t)
//    landed; STAGE(t+2->buf t&1) after ph3's end barrier guarantees all waves'
//    reads of buf t&1 completed (lgkm waits precede each phase's MFMAs).
// MODE 1: f32 C[M][N].  MODE 2: n0<2048 -> bf16 QK; n0>=2048 -> V^T epilogue
// (transpose via LDS 256x264, coalesced uint4 stores). XCD-chunked bid swizzle.
#define GTSTR 264
template <int MODE>
__global__ __launch_bounds__(512, 2) void gemm256_bf16(
    const unsigned short* __restrict__ A, const unsigned short* __restrict__ BT,
    const float* __restrict__ bias, void* __restrict__ Cout, void* __restrict__ Cout2,
    int M, int N, int K, int NXT)
{
    constexpr int SHSZ = (MODE == 2) ? 256*GTSTR : 65536;
    __shared__ __align__(16) unsigned short Sh[SHSZ];

    const int tid  = threadIdx.x;
    const int lane = tid & 63;
    const int wave = tid >> 6;               // 0..7
    const int wm = wave >> 2, wn = wave & 3; // 2 x 4 wave grid
    const int quad = lane >> 4, l16 = lane & 15;

    // XCD-chunked swizzle: each XCD gets contiguous wg range (A-panel L2 reuse)
    const int nwg = gridDim.x, cpx = nwg >> 3;
    const int wg = (blockIdx.x & 7)*cpx + (blockIdx.x >> 3);
    const int by = wg / NXT, bx = wg - by*NXT;
    const int m0 = by*256, n0 = bx*256;

    f32x4 acc[8][4] = {};
    const int nk = K >> 6;

    auto STAGE = [&](int t, int buf) {
        const int k0 = t << 6;
        unsigned short* Ab = &Sh[buf*16384];
        unsigned short* Bb = &Sh[32768 + buf*16384];
        #pragma unroll
        for (int p = 0; p < 4; ++p) {
            int c = p*512 + tid;                 // 16B chunk, linear in lane
            int row = c >> 3, ch = (c & 7) ^ (row & 7);
            GLOAD_LDS16(&A[(size_t)(m0 + row)*K + k0 + ch*8], &Ab[c*8]);
        }
        #pragma unroll
        for (int p = 0; p < 4; ++p) {
            int c = p*512 + tid;
            int row = c >> 3, ch = (c & 7) ^ (row & 7);
            GLOAD_LDS16(&BT[(size_t)(n0 + row)*K + k0 + ch*8], &Bb[c*8]);
        }
    };

    STAGE(0, 0);
    STAGE(1, 1);

    for (int t = 0; t < nk; ++t) {
        const int buf = t & 1;
        const unsigned short* Ab = &Sh[buf*16384];
        const unsigned short* Bb = &Sh[32768 + buf*16384];

        asm volatile("s_waitcnt vmcnt(8)" ::: "memory");  // tile t landed
        __builtin_amdgcn_s_barrier();
        __builtin_amdgcn_sched_barrier(0);                // no ds_read hoists above

        short8 fa[4][2], fb[2][2];
        auto LDA = [&](int mh) {
            #pragma unroll
            for (int mi = 0; mi < 4; ++mi)
                #pragma unroll
                for (int kk = 0; kk < 2; ++kk) {
                    int row = wm*128 + mh*64 + mi*16 + l16;
                    fa[mi][kk] = *(const short8*)&Ab[row*64 + (((kk*4 + quad) ^ (row & 7))*8)];
                }
        };
        auto LDB = [&](int nh) {
            #pragma unroll
            for (int ni = 0; ni < 2; ++ni)
                #pragma unroll
                for (int kk = 0; kk < 2; ++kk) {
                    int row = wn*64 + nh*32 + ni*16 + l16;
                    fb[ni][kk] = *(const short8*)&Bb[row*64 + (((kk*4 + quad) ^ (row & 7))*8)];
                }
        };

        // ---- phase 0: (m-lo, n-lo)
        LDA(0); LDB(0);
        __builtin_amdgcn_s_barrier();
        __builtin_amdgcn_s_setprio(1);
        #pragma unroll
        for (int mi = 0; mi < 4; ++mi)
            #pragma unroll
            for (int ni = 0; ni < 2; ++ni)
                #pragma unroll
                for (int kk = 0; kk < 2; ++kk)
                    acc[mi][ni] = __builtin_amdgcn_mfma_f32_16x16x32_bf16(
                        fa[mi][kk], fb[ni][kk], acc[mi][ni], 0, 0, 0);
        __builtin_amdgcn_s_setprio(0);
        __builtin_amdgcn_s_barrier();

        // ---- phase 1: (m-lo, n-hi)
        LDB(1);
        __builtin_amdgcn_s_barrier();
        __builtin_amdgcn_s_setprio(1);
        #pragma unroll
        for (int mi = 0; mi < 4; ++mi)
            #pragma unroll
            for (int ni = 0; ni < 2; ++ni)
                #pragma unroll
                for (int kk = 0; kk < 2; ++kk)
                    acc[mi][2 + ni] = __builtin_amdgcn_mfma_f32_16x16x32_bf16(
                        fa[mi][kk], fb[ni][kk], acc[mi][2 + ni], 0, 0, 0);
        __builtin_amdgcn_s_setprio(0);
        __builtin_amdgcn_s_barrier();

        // ---- phase 2: (m-hi, n-hi)
        LDA(1);
        __builtin_amdgcn_s_barrier();
        __builtin_amdgcn_s_setprio(1);
        #pragma unroll
        for (int mi = 0; mi < 4; ++mi)
            #pragma unroll
            for (int ni = 0; ni < 2; ++ni)
                #pragma unroll
                for (int kk = 0; kk < 2; ++kk)
                    acc[4 + mi][2 + ni] = __builtin_amdgcn_mfma_f32_16x16x32_bf16(
                        fa[mi][kk], fb[ni][kk], acc[4 + mi][2 + ni], 0, 0, 0);
        __builtin_amdgcn_s_setprio(0);
        __builtin_amdgcn_s_barrier();

        // ---- phase 3: (m-hi, n-lo)
        LDB(0);
        __builtin_amdgcn_s_barrier();
        __builtin_amdgcn_s_setprio(1);
        #pragma unroll
        for (int mi = 0; mi < 4; ++mi)
            #pragma unroll
            for (int ni = 0; ni < 2; ++ni)
                #pragma unroll
                for (int kk = 0; kk < 2; ++kk)
                    acc[4 + mi][ni] = __builtin_amdgcn_mfma_f32_16x16x32_bf16(
                        fa[mi][kk], fb[ni][kk], acc[4 + mi][ni], 0, 0, 0);
        __builtin_amdgcn_s_setprio(0);
        __builtin_amdgcn_s_barrier();          // all buf-t reads complete chip-wide

        __builtin_amdgcn_sched_barrier(0);     // STAGE must not hoist above
        if (t + 2 < nk) STAGE(t + 2, buf);     // prefetch 2 tiles ahead
    }

    if (MODE == 2 && n0 >= 2048) {
        // V third: transpose via LDS (no outstanding loads; last barrier passed)
        #pragma unroll
        for (int ni = 0; ni < 4; ++ni) {
            int nl = wn*64 + ni*16 + l16;          // local n 0..255
            float bv = bias[n0 + nl];
            #pragma unroll
            for (int mi = 0; mi < 8; ++mi) {
                ushort4 pk;
                pk.x = f2bf(acc[mi][ni][0] + bv);
                pk.y = f2bf(acc[mi][ni][1] + bv);
                pk.z = f2bf(acc[mi][ni][2] + bv);
                pk.w = f2bf(acc[mi][ni][3] + bv);
                *(ushort4*)&Sh[nl*GTSTR + wm*128 + mi*16 + quad*4] = pk;
            }
        }
        __builtin_amdgcn_s_barrier();
        const int bb = m0 >> 11, t0 = m0 & 2047;
        #pragma unroll
        for (int p = 0; p < 16; ++p) {
            int c = p*512 + tid;
            int row = c >> 5, ch = c & 31;         // row: local n, ch: 8-short m-chunk
            int nv = n0 + row - 2048;
            int hv = nv >> 6, dv = nv & 63;
            *(uint4*)&((unsigned short*)Cout2)[((size_t)((bb*16 + hv)*64 + dv))*2048 + t0 + ch*8] =
                *(uint4*)&Sh[row*GTSTR + ch*8];
        }
        return;
    }

    const int cstride = (MODE == 2) ? 2048 : N;
    #pragma unroll
    for (int ni = 0; ni < 4; ++ni) {
        int n = n0 + wn*64 + ni*16 + l16;
        float bv = bias[n];
        #pragma unroll
        for (int mi = 0; mi < 8; ++mi) {
            #pragma unroll
            for (int r = 0; r < 4; ++r) {
                int m = m0 + wm*128 + mi*16 + quad*4 + r;
                float val = acc[mi][ni][r] + bv;
                if (MODE == 1)
                    ((float*)Cout)[(size_t)m*cstride + n] = val;
                else
                    ((unsigned short*)Cout)[(size_t)m*cstride + n] = f2bf(val);
            }
        }
    }
}

// ---------------- MFMA flash attention: 4-wave block, LDS K+V, paired q-chunks ----
// (unchanged from round 4: best measured 122us. Uniform 34 k-tiles/block via
// complementary q-chunk pair (a, 15-a); K/V LDS dbuf, 2-phase pipeline, DPP
// softmax; XCD pinning i&7.)
#define PST 72
__global__ __launch_bounds__(256, 3) void attn_mfma(
    const unsigned short* __restrict__ QK, const unsigned short* __restrict__ VT,
    unsigned short* __restrict__ Y)
{
    // LDS: K dbuf 2x4096 shorts, V dbuf 2x4096 shorts, P 4 waves x 32 x PST
    __shared__ __align__(16) unsigned short Sh[16384 + 4*32*PST];

    const int tid  = threadIdx.x;
    const int lane = tid & 63;
    const int wave = tid >> 6;
    const int quad = lane >> 4, l16 = lane & 15;

    const int i = blockIdx.x;            // 0..511
    const int xcd = i & 7, j = i >> 3;   // j 0..63
    const int a = j & 7;                 // chunk-pair index: handles qc=a then 15-a
    const int u = j >> 3;                // bh-group 0..7
    const int bh2 = xcd + 8*u;
    const int b = bh2 >> 4, h = bh2 & 15;
    const size_t qkbase = (size_t)(b*TT) * 2048;
    const size_t vbase  = (size_t)(bh2*64) * 2048;
    const int qcol = h*64, kcol = 1024 + h*64;
    const float C2 = 0.18033688011112042f;   // (1/sqrt(64)) * log2(e)

    unsigned short* Pw = &Sh[16384 + wave*(32*PST)];

    const int nk1 = 2*a + 2;             // pass-0 tile count (qc = a)
    const int ntot = 34;                 // uniform for all blocks

    short8 aq[2][2];
    f32x4 o[2][4];
    float mold[2][4], lsum[2][4];
    int q0w = a*128 + wave*32;           // current pass q-row base for this wave

    auto LOADQ = [&]() {
        #pragma unroll
        for (int mt = 0; mt < 2; ++mt)
            #pragma unroll
            for (int kk = 0; kk < 2; ++kk)
                aq[mt][kk] = *(const short8*)&QK[qkbase + (size_t)(q0w + mt*16 + l16)*2048
                                                + qcol + kk*32 + quad*8];
        #pragma unroll
        for (int mt = 0; mt < 2; ++mt)
            #pragma unroll
            for (int r = 0; r < 4; ++r) { mold[mt][r] = -3.0e38f; lsum[mt][r] = 0.0f; }
        #pragma unroll
        for (int mt = 0; mt < 2; ++mt)
            #pragma unroll
            for (int dt = 0; dt < 4; ++dt) { f32x4 z = {}; o[mt][dt] = z; }
    };
    auto FINALIZE = [&]() {
        #pragma unroll
        for (int mt = 0; mt < 2; ++mt)
            #pragma unroll
            for (int r = 0; r < 4; ++r) {
                float inv = 1.0f / lsum[mt][r];
                int tq = q0w + mt*16 + quad*4 + r;
                #pragma unroll
                for (int dt = 0; dt < 4; ++dt)
                    Y[((size_t)(b*TT + tq))*DD + h*64 + dt*16 + l16] = f2bf(o[mt][dt][r] * inv);
            }
    };

    auto STAGE = [&](int buf, int k0) {
        unsigned short* Kb = &Sh[buf*4096];
        unsigned short* Vb = &Sh[8192 + buf*4096];
        #pragma unroll
        for (int p = 0; p < 2; ++p) {
            int c = p*256 + tid;               // 16B chunk index, linear in lane
            int r = c >> 3;
            int ch = (c & 7) ^ (r & 7);        // source chunk (inverse swizzle)
            GLOAD_LDS16(&QK[qkbase + (size_t)(k0 + r)*2048 + kcol + ch*8], &Kb[c*8]);
        }
        #pragma unroll
        for (int p = 0; p < 2; ++p) {
            int c = p*256 + tid;
            int r = c >> 3;                    // r = head-dim row of VT
            int ch = (c & 7) ^ (r & 7);
            GLOAD_LDS16(&VT[vbase + (size_t)r*2048 + k0 + ch*8], &Vb[c*8]);
        }
    };

    LOADQ();
    STAGE(0, 0);
    asm volatile("s_waitcnt vmcnt(0)" ::: "memory");
    __builtin_amdgcn_s_barrier();

    int cur = 0;
    for (int t = 0; t < ntot; ++t) {
        const int k0 = ((t < nk1) ? t : t - nk1) * 64;
        if (t + 1 < ntot) {
            const int t1 = t + 1;
            STAGE(cur ^ 1, ((t1 < nk1) ? t1 : t1 - nk1) * 64);   // async prefetch
        }
        if (t == nk1) {
            FINALIZE();
            q0w = (15 - a)*128 + wave*32;
            LOADQ();
        }

        if (k0 <= q0w + 31) {                  // wave-uniform causal activity guard
            const unsigned short* Kb = &Sh[cur*4096];
            const unsigned short* Vb = &Sh[8192 + cur*4096];

            // ---- S = Q K^T from LDS (swizzled reads)
            f32x4 s[2][4];
            #pragma unroll
            for (int nt = 0; nt < 4; ++nt) {
                if (k0 + nt*16 <= q0w + 31) {
                    f32x4 z = {};
                    s[0][nt] = z; s[1][nt] = z;
                    #pragma unroll
                    for (int kk = 0; kk < 2; ++kk) {
                        int r = nt*16 + l16;
                        short8 bk = *(const short8*)&Kb[r*64 + (((kk*4 + quad) ^ (r & 7))*8)];
                        s[0][nt] = __builtin_amdgcn_mfma_f32_16x16x32_bf16(aq[0][kk], bk, s[0][nt], 0, 0, 0);
                        s[1][nt] = __builtin_amdgcn_mfma_f32_16x16x32_bf16(aq[1][kk], bk, s[1][nt], 0, 0, 0);
                    }
                } else {
                    #pragma unroll
                    for (int r = 0; r < 4; ++r) { s[0][nt][r] = -3.0e38f; s[1][nt][r] = -3.0e38f; }
                }
            }

            // ---- issue V-frag LDS loads now; latency hides under softmax
            short8 bv[2][4];
            #pragma unroll
            for (int kk = 0; kk < 2; ++kk)
                #pragma unroll
                for (int dt = 0; dt < 4; ++dt) {
                    int r = dt*16 + l16;
                    bv[kk][dt] = *(const short8*)&Vb[r*64 + (((kk*4 + quad) ^ (r & 7))*8)];
                }

            // ---- element causal mask (straddling tiles only)
            if (k0 + 63 > q0w) {
                #pragma unroll
                for (int mt = 0; mt < 2; ++mt)
                    #pragma unroll
                    for (int nt = 0; nt < 4; ++nt)
                        #pragma unroll
                        for (int r = 0; r < 4; ++r) {
                            int kg = k0 + nt*16 + l16;
                            int qg = q0w + mt*16 + quad*4 + r;
                            if (kg > qg) s[mt][nt][r] = -3.0e38f;
                        }
            }

            // ---- online softmax (exp2 domain), DPP reductions
            float m2n[2][4], al[2][4];
            #pragma unroll
            for (int mt = 0; mt < 2; ++mt)
                #pragma unroll
                for (int r = 0; r < 4; ++r) {
                    float rm = fmaxf(fmaxf(s[mt][0][r], s[mt][1][r]),
                                     fmaxf(s[mt][2][r], s[mt][3][r]));
                    rm = red_max16(rm);
                    float m2 = fmaxf(mold[mt][r], rm * C2);
                    al[mt][r]  = EXP2(mold[mt][r] - m2);
                    m2n[mt][r] = m2;
                }
            float rs[2][4] = {};
            #pragma unroll
            for (int mt = 0; mt < 2; ++mt)
                #pragma unroll
                for (int nt = 0; nt < 4; ++nt)
                    #pragma unroll
                    for (int r = 0; r < 4; ++r) {
                        float p = EXP2(fmaf(s[mt][nt][r], C2, -m2n[mt][r]));
                        s[mt][nt][r] = p;
                        rs[mt][r] += p;
                    }
            #pragma unroll
            for (int mt = 0; mt < 2; ++mt)
                #pragma unroll
                for (int r = 0; r < 4; ++r) {
                    float tsum = red_sum16(rs[mt][r]);
                    lsum[mt][r] = lsum[mt][r]*al[mt][r] + tsum;
                    mold[mt][r] = m2n[mt][r];
                }

            // ---- P -> LDS (wave-private buffer; same-wave RAW, no barrier)
            #pragma unroll
            for (int mt = 0; mt < 2; ++mt)
                #pragma unroll
                for (int nt = 0; nt < 4; ++nt)
                    #pragma unroll
                    for (int r = 0; r < 4; ++r) {
                        union { float f; uint32_t u; } c; c.f = s[mt][nt][r];
                        Pw[(mt*16 + quad*4 + r)*PST + nt*16 + l16] =
                            (unsigned short)((c.u + 0x8000u) >> 16);
                    }

            // ---- O = O*alpha + P V
            #pragma unroll
            for (int mt = 0; mt < 2; ++mt)
                #pragma unroll
                for (int dt = 0; dt < 4; ++dt)
                    #pragma unroll
                    for (int r = 0; r < 4; ++r)
                        o[mt][dt][r] *= al[mt][r];
            #pragma unroll
            for (int kk = 0; kk < 2; ++kk) {
                short8 ap0 = *(short8*)&Pw[(     l16)*PST + kk*32 + quad*8];
                short8 ap1 = *(short8*)&Pw[(16 + l16)*PST + kk*32 + quad*8];
                #pragma unroll
                for (int dt = 0; dt < 4; ++dt) {
                    o[0][dt] = __builtin_amdgcn_mfma_f32_16x16x32_bf16(ap0, bv[kk][dt], o[0][dt], 0, 0, 0);
                    o[1][dt] = __builtin_amdgcn_mfma_f32_16x16x32_bf16(ap1, bv[kk][dt], o[1][dt], 0, 0, 0);
                }
            }
        }

        asm volatile("s_waitcnt vmcnt(0)" ::: "memory");  // next-tile stage landed
        __builtin_amdgcn_s_barrier();                     // all waves' stage + reads done
        cur ^= 1;
    }

    FINALIZE();   // pass-1 (chunk 15-a) output
}

extern "C" void kernel_launch(void* const* d_in, const int* in_sizes, int n_in,
                              void* d_out, int out_size, void* d_ws, size_t ws_size,
                              hipStream_t stream)
{
    const float* x    = (const float*)d_in[0];   // [4,2048,1024] fp32
    // d_in[1] = causal_mask (int32) — causality implemented analytically, unused
    const float* wqkv = (const float*)d_in[2];   // [1024][3072] fp32
    const float* bqkv = (const float*)d_in[3];   // [3072] fp32
    const float* wout = (const float*)d_in[4];   // [1024][1024] fp32
    const float* bout = (const float*)d_in[5];   // [1024] fp32
    float* out = (float*)d_out;                  // [4,2048,1024] fp32

    char* ws = (char*)d_ws;
    unsigned short* Xb    = (unsigned short*)ws;                    // 16 MB
    unsigned short* WqkvT = (unsigned short*)(ws + 16777216);       // 6 MB
    unsigned short* WoutT = (unsigned short*)(ws + 23068672);       // 2 MB
    unsigned short* QK    = (unsigned short*)(ws + 25165824);       // 32 MB [M][2048]
    unsigned short* VTb   = (unsigned short*)(ws + 58720256);       // 16 MB [(bh*64+d)][2048]
    unsigned short* Ybuf  = (unsigned short*)(ws + 75497472);       // 16 MB

    cvt_f32_bf16<<<(M1*KDIM/4 + 255)/256, 256, 0, stream>>>(x, Xb, M1*KDIM/4);
    transpose_f32_bf16<<<dim3(N1/32, KDIM/32), dim3(32, 8), 0, stream>>>(wqkv, WqkvT, KDIM, N1);
    transpose_f32_bf16<<<dim3(DD/32, KDIM/32), dim3(32, 8), 0, stream>>>(wout, WoutT, KDIM, DD);
    gemm256_bf16<2><<<dim3(384), 512, 0, stream>>>(Xb, WqkvT, bqkv, QK, VTb, M1, N1, KDIM, 12);
    attn_mfma<<<dim3(512), 256, 0, stream>>>(QK, VTb, Ybuf);
    gemm256_bf16<1><<<dim3(128), 512, 0, stream>>>(Ybuf, WoutT, bout, out, nullptr, M1, DD, KDIM, 4);
}

// Round 6
// 313.747 us; speedup vs baseline: 1.5754x; 1.0633x over previous
//
#include <hip/hip_runtime.h>
#include <hip/hip_bf16.h>
#include <stdint.h>

// Problem constants
#define BB 4
#define TT 2048
#define DD 1024
#define HH 16
#define HDD 64
// derived
#define M1 (BB*TT)      // 8192 rows
#define N1 (3*DD)       // 3072
#define KDIM DD         // 1024

typedef __attribute__((ext_vector_type(8))) short short8;   // 8 bf16 MFMA operand
typedef __attribute__((ext_vector_type(4))) float f32x4;

#if __has_builtin(__builtin_amdgcn_exp2f)
#define EXP2(x) __builtin_amdgcn_exp2f(x)
#else
#define EXP2(x) exp2f(x)
#endif

// async global->LDS, 16B per lane (global_load_lds_dwordx4)
#define GLOAD_LDS16(gp, lp) \
    __builtin_amdgcn_global_load_lds( \
        (const __attribute__((address_space(1))) void*)(gp), \
        (__attribute__((address_space(3))) void*)(lp), 16, 0, 0)

__device__ __forceinline__ float bf2f(unsigned short u) {
    union { uint32_t u32; float f; } c; c.u32 = ((uint32_t)u) << 16; return c.f;
}
__device__ __forceinline__ unsigned short f2bf(float f) {
    union { float f; uint32_t u32; } c; c.f = f;
    uint32_t u = c.u32;
    return (unsigned short)((u + 0x7FFFu + ((u >> 16) & 1u)) >> 16);  // RNE
}

// DPP row_ror rotate-reduce within the 16-lane DPP row.
template <int CTRL>
__device__ __forceinline__ float dpp_ror(float x) {
    union { float f; int i; } u, r;
    u.f = x;
    r.i = __builtin_amdgcn_update_dpp(u.i, u.i, CTRL, 0xF, 0xF, false);
    return r.f;
}
__device__ __forceinline__ float red_max16(float x) {
    x = fmaxf(x, dpp_ror<0x128>(x));   // row_ror:8
    x = fmaxf(x, dpp_ror<0x124>(x));   // row_ror:4
    x = fmaxf(x, dpp_ror<0x122>(x));   // row_ror:2
    x = fmaxf(x, dpp_ror<0x121>(x));   // row_ror:1
    return x;
}
__device__ __forceinline__ float red_sum16(float x) {
    x += dpp_ror<0x128>(x);
    x += dpp_ror<0x124>(x);
    x += dpp_ror<0x122>(x);
    x += dpp_ror<0x121>(x);
    return x;
}

// ---------------- elementwise fp32 -> bf16 (x), 4 elems/thread ----------------
__global__ __launch_bounds__(256) void cvt_f32_bf16(
    const float* __restrict__ in, unsigned short* __restrict__ out, int n4)
{
    int i = blockIdx.x * 256 + threadIdx.x;
    if (i >= n4) return;
    float4 v = *(const float4*)&in[(size_t)i * 4];
    ushort4 o;
    o.x = f2bf(v.x); o.y = f2bf(v.y); o.z = f2bf(v.z); o.w = f2bf(v.w);
    *(ushort4*)&out[(size_t)i * 4] = o;
}

// ---------------- transpose+convert: in fp32 [R][C] -> out bf16 [C][R] ----------------
__global__ __launch_bounds__(256) void transpose_f32_bf16(
    const float* __restrict__ in, unsigned short* __restrict__ out,
    int R, int C)
{
    __shared__ unsigned short tile[32][33];
    int bx = blockIdx.x;
    int by = blockIdx.y;
    int x = bx*32 + threadIdx.x;
    int y0 = by*32 + threadIdx.y;
    #pragma unroll
    for (int i = 0; i < 32; i += 8)
        tile[threadIdx.y + i][threadIdx.x] = f2bf(in[(size_t)(y0 + i)*C + x]);
    __syncthreads();
    int xo = by*32 + threadIdx.x;
    int yo = bx*32 + threadIdx.y;
    #pragma unroll
    for (int i = 0; i < 32; i += 8)
        out[(size_t)(yo + i)*R + xo] = tile[threadIdx.x][threadIdx.y + i];
}

// ---------------- big-tile MFMA bf16 GEMM, counted-vmcnt pipeline ----------------
// Round-5 post-mortem: 256x256 tiling gave grid 384 (QKV, 1.5 blocks/CU ->
// 25% idle tail) and 128 (out-proj, HALF the CUs idle). This round keeps the
// schedule, templatizes the tile:
//   QKV:      BM=256 x BN=128 -> grid 768 = 3 blocks/CU EXACT
//   out-proj: BM=128 x BN=256 -> grid 256 = 1 block/CU EXACT
// 8 waves x (64x64 per-wave tile) = acc[4][4] (64 acc VGPRs, more headroom
// than round 5's 128). LDS (BM+BN)*64*2B*2buf = 96 KB -> 1 block/CU by LDS.
//  - T2 swizzle: chunk ^= row&7 on stage SOURCE + same XOR on ds_read_b128.
//  - T4 counted vmcnt: 6 loads/tile; tile top s_waitcnt vmcnt(6) + raw
//    s_barrier + sched_barrier(0). LAST tile waits vmcnt(0) (round-5 bug:
//    vmcnt(8) was a no-op there -> final-tile ds_reads unordered vs stage).
//  - 2 phases/tile: {ds_read A-all + B-lo, bar, setprio, 16 MFMA, bar} then
//    {ds_read B-hi, bar, setprio, 16 MFMA, bar}. STAGE(t+2) after last bar.
//  - Race-freedom: each wave's MFMAs consume its ds_reads (lgkm waits) before
//    it reaches the phase-end barrier, so STAGE(t+2) overwriting buf t&1 after
//    that barrier is WAR-safe; tile-top vmcnt+barrier gives RAW.
// MODE 1: f32 C[M][N].  MODE 2: n0<2048 -> bf16 QK; n0>=2048 -> V^T epilogue
// (transpose via LDS BN x (BM+8), coalesced uint4 stores). XCD-chunked swizzle.
template <int MODE, int BM, int BN>
__global__ __launch_bounds__(512, 2) void gemm_big(
    const unsigned short* __restrict__ A, const unsigned short* __restrict__ BT,
    const float* __restrict__ bias, void* __restrict__ Cout, void* __restrict__ Cout2,
    int K, int N, int NXT)
{
    constexpr int SHSZ = 2*(BM+BN)*64;               // shorts; 96 KB
    __shared__ __align__(16) unsigned short Sh[SHSZ];

    const int tid  = threadIdx.x;
    const int lane = tid & 63;
    const int wave = tid >> 6;                       // 0..7
    constexpr int WNG = BN/64;                       // waves along n
    const int wm = wave / WNG, wn = wave % WNG;
    const int quad = lane >> 4, l16 = lane & 15;

    // XCD-chunked swizzle: each XCD gets a contiguous wg range (A-panel reuse)
    const int nwg = gridDim.x, cpx = nwg >> 3;
    const int wg = (blockIdx.x & 7)*cpx + (blockIdx.x >> 3);
    const int by = wg / NXT, bx = wg - by*NXT;
    const int m0 = by*BM, n0 = bx*BN;

    f32x4 acc[4][4] = {};
    const int nk = K >> 6;

    auto STAGE = [&](int t, int buf) {
        const int k0 = t << 6;
        unsigned short* Ab = &Sh[buf*(BM*64)];
        unsigned short* Bb = &Sh[2*BM*64 + buf*(BN*64)];
        #pragma unroll
        for (int p = 0; p < BM/64; ++p) {            // BM*8 chunks / 512 thr
            int c = p*512 + tid;
            int row = c >> 3, ch = (c & 7) ^ (row & 7);
            GLOAD_LDS16(&A[(size_t)(m0 + row)*K + k0 + ch*8], &Ab[c*8]);
        }
        #pragma unroll
        for (int p = 0; p < BN/64; ++p) {
            int c = p*512 + tid;
            int row = c >> 3, ch = (c & 7) ^ (row & 7);
            GLOAD_LDS16(&BT[(size_t)(n0 + row)*K + k0 + ch*8], &Bb[c*8]);
        }
    };

    STAGE(0, 0);
    STAGE(1, 1);

    for (int t = 0; t < nk; ++t) {
        const int buf = t & 1;
        const unsigned short* Ab = &Sh[buf*(BM*64)];
        const unsigned short* Bb = &Sh[2*BM*64 + buf*(BN*64)];

        if (t == nk - 1) asm volatile("s_waitcnt vmcnt(0)" ::: "memory");
        else             asm volatile("s_waitcnt vmcnt(6)" ::: "memory");
        __builtin_amdgcn_s_barrier();
        __builtin_amdgcn_sched_barrier(0);           // no ds_read hoists above

        short8 fa[4][2], fb[2][2];

        // ---- phase 0: all m x n-lo
        #pragma unroll
        for (int mi = 0; mi < 4; ++mi)
            #pragma unroll
            for (int kk = 0; kk < 2; ++kk) {
                int row = wm*64 + mi*16 + l16;
                fa[mi][kk] = *(const short8*)&Ab[row*64 + (((kk*4 + quad) ^ (row & 7))*8)];
            }
        #pragma unroll
        for (int ni = 0; ni < 2; ++ni)
            #pragma unroll
            for (int kk = 0; kk < 2; ++kk) {
                int row = wn*64 + ni*16 + l16;
                fb[ni][kk] = *(const short8*)&Bb[row*64 + (((kk*4 + quad) ^ (row & 7))*8)];
            }
        __builtin_amdgcn_s_barrier();
        __builtin_amdgcn_s_setprio(1);
        #pragma unroll
        for (int mi = 0; mi < 4; ++mi)
            #pragma unroll
            for (int ni = 0; ni < 2; ++ni)
                #pragma unroll
                for (int kk = 0; kk < 2; ++kk)
                    acc[mi][ni] = __builtin_amdgcn_mfma_f32_16x16x32_bf16(
                        fa[mi][kk], fb[ni][kk], acc[mi][ni], 0, 0, 0);
        __builtin_amdgcn_s_setprio(0);
        __builtin_amdgcn_s_barrier();

        // ---- phase 1: all m x n-hi
        #pragma unroll
        for (int ni = 0; ni < 2; ++ni)
            #pragma unroll
            for (int kk = 0; kk < 2; ++kk) {
                int row = wn*64 + 32 + ni*16 + l16;
                fb[ni][kk] = *(const short8*)&Bb[row*64 + (((kk*4 + quad) ^ (row & 7))*8)];
            }
        __builtin_amdgcn_s_barrier();
        __builtin_amdgcn_s_setprio(1);
        #pragma unroll
        for (int mi = 0; mi < 4; ++mi)
            #pragma unroll
            for (int ni = 0; ni < 2; ++ni)
                #pragma unroll
                for (int kk = 0; kk < 2; ++kk)
                    acc[mi][2 + ni] = __builtin_amdgcn_mfma_f32_16x16x32_bf16(
                        fa[mi][kk], fb[ni][kk], acc[mi][2 + ni], 0, 0, 0);
        __builtin_amdgcn_s_setprio(0);
        __builtin_amdgcn_s_barrier();                // all buf-t reads consumed

        __builtin_amdgcn_sched_barrier(0);           // STAGE must not hoist above
        if (t + 2 < nk) STAGE(t + 2, buf);           // prefetch 2 tiles ahead
    }

    if (MODE == 2 && n0 >= 2048) {
        // V third: transpose via LDS (all staging reads consumed; vm drained)
        constexpr int STR = BM + 8;
        #pragma unroll
        for (int ni = 0; ni < 4; ++ni) {
            int nl = wn*64 + ni*16 + l16;            // local n 0..BN-1
            float bv = bias[n0 + nl];
            #pragma unroll
            for (int mi = 0; mi < 4; ++mi) {
                ushort4 pk;
                pk.x = f2bf(acc[mi][ni][0] + bv);
                pk.y = f2bf(acc[mi][ni][1] + bv);
                pk.z = f2bf(acc[mi][ni][2] + bv);
                pk.w = f2bf(acc[mi][ni][3] + bv);
                *(ushort4*)&Sh[nl*STR + wm*64 + mi*16 + quad*4] = pk;
            }
        }
        __builtin_amdgcn_s_barrier();
        const int bb = m0 >> 11, t0 = m0 & 2047;
        constexpr int CHROW = BM/8;                  // 16B chunks per n-row
        constexpr int NIT = BN*CHROW/512;
        #pragma unroll
        for (int p = 0; p < NIT; ++p) {
            int c = p*512 + tid;
            int row = c / CHROW, ch = c % CHROW;     // row: local n
            int nv = n0 + row - 2048;
            int hv = nv >> 6, dv = nv & 63;
            *(uint4*)&((unsigned short*)Cout2)[((size_t)((bb*16 + hv)*64 + dv))*2048 + t0 + ch*8] =
                *(uint4*)&Sh[row*STR + ch*8];
        }
        return;
    }

    const int cstride = (MODE == 2) ? 2048 : N;
    #pragma unroll
    for (int ni = 0; ni < 4; ++ni) {
        int n = n0 + wn*64 + ni*16 + l16;
        float bv = bias[n];
        #pragma unroll
        for (int mi = 0; mi < 4; ++mi) {
            #pragma unroll
            for (int r = 0; r < 4; ++r) {
                int m = m0 + wm*64 + mi*16 + quad*4 + r;
                float val = acc[mi][ni][r] + bv;
                if (MODE == 1)
                    ((float*)Cout)[(size_t)m*cstride + n] = val;
                else
                    ((unsigned short*)Cout)[(size_t)m*cstride + n] = f2bf(val);
            }
        }
    }
}

// ---------------- MFMA flash attention: 4-wave block, LDS K+V, paired q-chunks ----
// (unchanged from round 4: best measured 122us. Uniform 34 k-tiles/block via
// complementary q-chunk pair (a, 15-a); K/V LDS dbuf, 2-phase pipeline, DPP
// softmax; XCD pinning i&7.)
#define PST 72
__global__ __launch_bounds__(256, 3) void attn_mfma(
    const unsigned short* __restrict__ QK, const unsigned short* __restrict__ VT,
    unsigned short* __restrict__ Y)
{
    // LDS: K dbuf 2x4096 shorts, V dbuf 2x4096 shorts, P 4 waves x 32 x PST
    __shared__ __align__(16) unsigned short Sh[16384 + 4*32*PST];

    const int tid  = threadIdx.x;
    const int lane = tid & 63;
    const int wave = tid >> 6;
    const int quad = lane >> 4, l16 = lane & 15;

    const int i = blockIdx.x;            // 0..511
    const int xcd = i & 7, j = i >> 3;   // j 0..63
    const int a = j & 7;                 // chunk-pair index: handles qc=a then 15-a
    const int u = j >> 3;                // bh-group 0..7
    const int bh2 = xcd + 8*u;
    const int b = bh2 >> 4, h = bh2 & 15;
    const size_t qkbase = (size_t)(b*TT) * 2048;
    const size_t vbase  = (size_t)(bh2*64) * 2048;
    const int qcol = h*64, kcol = 1024 + h*64;
    const float C2 = 0.18033688011112042f;   // (1/sqrt(64)) * log2(e)

    unsigned short* Pw = &Sh[16384 + wave*(32*PST)];

    const int nk1 = 2*a + 2;             // pass-0 tile count (qc = a)
    const int ntot = 34;                 // uniform for all blocks

    short8 aq[2][2];
    f32x4 o[2][4];
    float mold[2][4], lsum[2][4];
    int q0w = a*128 + wave*32;           // current pass q-row base for this wave

    auto LOADQ = [&]() {
        #pragma unroll
        for (int mt = 0; mt < 2; ++mt)
            #pragma unroll
            for (int kk = 0; kk < 2; ++kk)
                aq[mt][kk] = *(const short8*)&QK[qkbase + (size_t)(q0w + mt*16 + l16)*2048
                                                + qcol + kk*32 + quad*8];
        #pragma unroll
        for (int mt = 0; mt < 2; ++mt)
            #pragma unroll
            for (int r = 0; r < 4; ++r) { mold[mt][r] = -3.0e38f; lsum[mt][r] = 0.0f; }
        #pragma unroll
        for (int mt = 0; mt < 2; ++mt)
            #pragma unroll
            for (int dt = 0; dt < 4; ++dt) { f32x4 z = {}; o[mt][dt] = z; }
    };
    auto FINALIZE = [&]() {
        #pragma unroll
        for (int mt = 0; mt < 2; ++mt)
            #pragma unroll
            for (int r = 0; r < 4; ++r) {
                float inv = 1.0f / lsum[mt][r];
                int tq = q0w + mt*16 + quad*4 + r;
                #pragma unroll
                for (int dt = 0; dt < 4; ++dt)
                    Y[((size_t)(b*TT + tq))*DD + h*64 + dt*16 + l16] = f2bf(o[mt][dt][r] * inv);
            }
    };

    auto STAGE = [&](int buf, int k0) {
        unsigned short* Kb = &Sh[buf*4096];
        unsigned short* Vb = &Sh[8192 + buf*4096];
        #pragma unroll
        for (int p = 0; p < 2; ++p) {
            int c = p*256 + tid;               // 16B chunk index, linear in lane
            int r = c >> 3;
            int ch = (c & 7) ^ (r & 7);        // source chunk (inverse swizzle)
            GLOAD_LDS16(&QK[qkbase + (size_t)(k0 + r)*2048 + kcol + ch*8], &Kb[c*8]);
        }
        #pragma unroll
        for (int p = 0; p < 2; ++p) {
            int c = p*256 + tid;
            int r = c >> 3;                    // r = head-dim row of VT
            int ch = (c & 7) ^ (r & 7);
            GLOAD_LDS16(&VT[vbase + (size_t)r*2048 + k0 + ch*8], &Vb[c*8]);
        }
    };

    LOADQ();
    STAGE(0, 0);
    asm volatile("s_waitcnt vmcnt(0)" ::: "memory");
    __builtin_amdgcn_s_barrier();

    int cur = 0;
    for (int t = 0; t < ntot; ++t) {
        const int k0 = ((t < nk1) ? t : t - nk1) * 64;
        if (t + 1 < ntot) {
            const int t1 = t + 1;
            STAGE(cur ^ 1, ((t1 < nk1) ? t1 : t1 - nk1) * 64);   // async prefetch
        }
        if (t == nk1) {
            FINALIZE();
            q0w = (15 - a)*128 + wave*32;
            LOADQ();
        }

        if (k0 <= q0w + 31) {                  // wave-uniform causal activity guard
            const unsigned short* Kb = &Sh[cur*4096];
            const unsigned short* Vb = &Sh[8192 + cur*4096];

            // ---- S = Q K^T from LDS (swizzled reads)
            f32x4 s[2][4];
            #pragma unroll
            for (int nt = 0; nt < 4; ++nt) {
                if (k0 + nt*16 <= q0w + 31) {
                    f32x4 z = {};
                    s[0][nt] = z; s[1][nt] = z;
                    #pragma unroll
                    for (int kk = 0; kk < 2; ++kk) {
                        int r = nt*16 + l16;
                        short8 bk = *(const short8*)&Kb[r*64 + (((kk*4 + quad) ^ (r & 7))*8)];
                        s[0][nt] = __builtin_amdgcn_mfma_f32_16x16x32_bf16(aq[0][kk], bk, s[0][nt], 0, 0, 0);
                        s[1][nt] = __builtin_amdgcn_mfma_f32_16x16x32_bf16(aq[1][kk], bk, s[1][nt], 0, 0, 0);
                    }
                } else {
                    #pragma unroll
                    for (int r = 0; r < 4; ++r) { s[0][nt][r] = -3.0e38f; s[1][nt][r] = -3.0e38f; }
                }
            }

            // ---- issue V-frag LDS loads now; latency hides under softmax
            short8 bv[2][4];
            #pragma unroll
            for (int kk = 0; kk < 2; ++kk)
                #pragma unroll
                for (int dt = 0; dt < 4; ++dt) {
                    int r = dt*16 + l16;
                    bv[kk][dt] = *(const short8*)&Vb[r*64 + (((kk*4 + quad) ^ (r & 7))*8)];
                }

            // ---- element causal mask (straddling tiles only)
            if (k0 + 63 > q0w) {
                #pragma unroll
                for (int mt = 0; mt < 2; ++mt)
                    #pragma unroll
                    for (int nt = 0; nt < 4; ++nt)
                        #pragma unroll
                        for (int r = 0; r < 4; ++r) {
                            int kg = k0 + nt*16 + l16;
                            int qg = q0w + mt*16 + quad*4 + r;
                            if (kg > qg) s[mt][nt][r] = -3.0e38f;
                        }
            }

            // ---- online softmax (exp2 domain), DPP reductions
            float m2n[2][4], al[2][4];
            #pragma unroll
            for (int mt = 0; mt < 2; ++mt)
                #pragma unroll
                for (int r = 0; r < 4; ++r) {
                    float rm = fmaxf(fmaxf(s[mt][0][r], s[mt][1][r]),
                                     fmaxf(s[mt][2][r], s[mt][3][r]));
                    rm = red_max16(rm);
                    float m2 = fmaxf(mold[mt][r], rm * C2);
                    al[mt][r]  = EXP2(mold[mt][r] - m2);
                    m2n[mt][r] = m2;
                }
            float rs[2][4] = {};
            #pragma unroll
            for (int mt = 0; mt < 2; ++mt)
                #pragma unroll
                for (int nt = 0; nt < 4; ++nt)
                    #pragma unroll
                    for (int r = 0; r < 4; ++r) {
                        float p = EXP2(fmaf(s[mt][nt][r], C2, -m2n[mt][r]));
                        s[mt][nt][r] = p;
                        rs[mt][r] += p;
                    }
            #pragma unroll
            for (int mt = 0; mt < 2; ++mt)
                #pragma unroll
                for (int r = 0; r < 4; ++r) {
                    float tsum = red_sum16(rs[mt][r]);
                    lsum[mt][r] = lsum[mt][r]*al[mt][r] + tsum;
                    mold[mt][r] = m2n[mt][r];
                }

            // ---- P -> LDS (wave-private buffer; same-wave RAW, no barrier)
            #pragma unroll
            for (int mt = 0; mt < 2; ++mt)
                #pragma unroll
                for (int nt = 0; nt < 4; ++nt)
                    #pragma unroll
                    for (int r = 0; r < 4; ++r) {
                        union { float f; uint32_t u; } c; c.f = s[mt][nt][r];
                        Pw[(mt*16 + quad*4 + r)*PST + nt*16 + l16] =
                            (unsigned short)((c.u + 0x8000u) >> 16);
                    }

            // ---- O = O*alpha + P V
            #pragma unroll
            for (int mt = 0; mt < 2; ++mt)
                #pragma unroll
                for (int dt = 0; dt < 4; ++dt)
                    #pragma unroll
                    for (int r = 0; r < 4; ++r)
                        o[mt][dt][r] *= al[mt][r];
            #pragma unroll
            for (int kk = 0; kk < 2; ++kk) {
                short8 ap0 = *(short8*)&Pw[(     l16)*PST + kk*32 + quad*8];
                short8 ap1 = *(short8*)&Pw[(16 + l16)*PST + kk*32 + quad*8];
                #pragma unroll
                for (int dt = 0; dt < 4; ++dt) {
                    o[0][dt] = __builtin_amdgcn_mfma_f32_16x16x32_bf16(ap0, bv[kk][dt], o[0][dt], 0, 0, 0);
                    o[1][dt] = __builtin_amdgcn_mfma_f32_16x16x32_bf16(ap1, bv[kk][dt], o[1][dt], 0, 0, 0);
                }
            }
        }

        asm volatile("s_waitcnt vmcnt(0)" ::: "memory");  // next-tile stage landed
        __builtin_amdgcn_s_barrier();                     // all waves' stage + reads done
        cur ^= 1;
    }

    FINALIZE();   // pass-1 (chunk 15-a) output
}

extern "C" void kernel_launch(void* const* d_in, const int* in_sizes, int n_in,
                              void* d_out, int out_size, void* d_ws, size_t ws_size,
                              hipStream_t stream)
{
    const float* x    = (const float*)d_in[0];   // [4,2048,1024] fp32
    // d_in[1] = causal_mask (int32) — causality implemented analytically, unused
    const float* wqkv = (const float*)d_in[2];   // [1024][3072] fp32
    const float* bqkv = (const float*)d_in[3];   // [3072] fp32
    const float* wout = (const float*)d_in[4];   // [1024][1024] fp32
    const float* bout = (const float*)d_in[5];   // [1024] fp32
    float* out = (float*)d_out;                  // [4,2048,1024] fp32

    char* ws = (char*)d_ws;
    unsigned short* Xb    = (unsigned short*)ws;                    // 16 MB
    unsigned short* WqkvT = (unsigned short*)(ws + 16777216);       // 6 MB
    unsigned short* WoutT = (unsigned short*)(ws + 23068672);       // 2 MB
    unsigned short* QK    = (unsigned short*)(ws + 25165824);       // 32 MB [M][2048]
    unsigned short* VTb   = (unsigned short*)(ws + 58720256);       // 16 MB [(bh*64+d)][2048]
    unsigned short* Ybuf  = (unsigned short*)(ws + 75497472);       // 16 MB

    cvt_f32_bf16<<<(M1*KDIM/4 + 255)/256, 256, 0, stream>>>(x, Xb, M1*KDIM/4);
    transpose_f32_bf16<<<dim3(N1/32, KDIM/32), dim3(32, 8), 0, stream>>>(wqkv, WqkvT, KDIM, N1);
    transpose_f32_bf16<<<dim3(DD/32, KDIM/32), dim3(32, 8), 0, stream>>>(wout, WoutT, KDIM, DD);
    gemm_big<2, 256, 128><<<dim3(768), 512, 0, stream>>>(Xb, WqkvT, bqkv, QK, VTb, KDIM, N1, 24);
    attn_mfma<<<dim3(512), 256, 0, stream>>>(QK, VTb, Ybuf);
    gemm_big<1, 128, 256><<<dim3(256), 512, 0, stream>>>(Ybuf, WoutT, bout, out, nullptr, KDIM, DD, 4);
}